// Round 1
// 633.808 us; speedup vs baseline: 1.0215x; 1.0215x over previous
//
#include <hip/hip_runtime.h>

typedef __attribute__((ext_vector_type(8))) short bf16x8;
typedef __attribute__((ext_vector_type(4))) float f32x4;

__device__ __forceinline__ unsigned short f2b(float f) {
    union { float f; unsigned int i; } u; u.f = f;
    return (unsigned short)((u.i + 0x7FFFu + ((u.i >> 16) & 1u)) >> 16);
}
__device__ __forceinline__ unsigned int packbf2(float a, float b) {
    return (unsigned int)f2b(a) | ((unsigned int)f2b(b) << 16);
}

// ---------------------------------------------------------------------------
// ego -> bf16 copy (packed 2/uint). Streaming, grid-stride.
// ---------------------------------------------------------------------------
__global__ __launch_bounds__(256) void ego2bf16_kernel(
    const float* __restrict__ ego, unsigned int* __restrict__ egob, size_t n4)
{
    size_t i = (size_t)blockIdx.x * 256 + threadIdx.x;
    size_t stride = (size_t)gridDim.x * 256;
    for (; i < n4; i += stride) {
        float4 a = *(const float4*)(ego + i * 4);
        uint2 p;
        p.x = packbf2(a.x, a.y);
        p.y = packbf2(a.z, a.w);
        *(uint2*)(egob + i * 2) = p;
    }
}

// ---------------------------------------------------------------------------
// SpMM: side[r,:] += vals[e] * ego_bf16[cols[e],:]  (rows sorted). Block = 256
// threads = 4 waves; each wave owns 64 edges; lane holds 2 columns packed in
// one dword (bf16x2) -> 256 B/row gather instead of 512 B. Accumulation and
// atomics stay fp32. Depth-8 register prefetch queue for MLP.
// ---------------------------------------------------------------------------
__global__ __launch_bounds__(256) void spmm_kernel(
    const unsigned int* __restrict__ egob, const float* __restrict__ vals,
    const int* __restrict__ rows, const int* __restrict__ cols,
    float* __restrict__ side, int nnz)
{
    __shared__ int s_row[256];
    __shared__ int s_col[256];
    __shared__ float s_val[256];
    int e0 = blockIdx.x * 256;
    int n = nnz - e0; if (n > 256) n = 256;
    int tid = threadIdx.x;
    if (tid < n) {
        s_row[tid] = rows[e0 + tid];
        s_col[tid] = cols[e0 + tid];
        s_val[tid] = vals[e0 + tid];
    }
    __syncthreads();

    int wave = tid >> 6, lane = tid & 63;
    int base = wave * 64;
    int cnt = n - base; if (cnt > 64) cnt = 64;
    if (cnt <= 0) return;

    unsigned int pre[8];
    #pragma unroll
    for (int j = 0; j < 8; ++j)
        pre[j] = (j < cnt) ? egob[(size_t)s_col[base + j] * 64 + lane] : 0u;

    float ax = 0.f, ay = 0.f;
    int cur = s_row[base];
    for (int eo = 0; eo < 64; eo += 8) {
        if (eo >= cnt) break;
        #pragma unroll
        for (int j = 0; j < 8; ++j) {
            int e = eo + j;
            if (e < cnt) {
                int r = s_row[base + e];
                float vv = s_val[base + e];
                unsigned int u = pre[j];
                int nx = e + 8;
                if (nx < cnt)
                    pre[j] = egob[(size_t)s_col[base + nx] * 64 + lane];
                if (r != cur) {
                    atomicAdd(&side[(size_t)cur * 128 + lane * 2], ax);
                    atomicAdd(&side[(size_t)cur * 128 + lane * 2 + 1], ay);
                    ax = 0.f; ay = 0.f; cur = r;
                }
                ax = fmaf(vv, __uint_as_float(u << 16), ax);
                ay = fmaf(vv, __uint_as_float(u & 0xFFFF0000u), ay);
            }
        }
    }
    atomicAdd(&side[(size_t)cur * 128 + lane * 2], ax);
    atomicAdd(&side[(size_t)cur * 128 + lane * 2 + 1], ay);
}

// ---------------------------------------------------------------------------
// MFMA GEMM core: C[bm:bm+128, bn:bn+64] = act(A@W + bias [+R]).
// A f32 (M,K) row-major, W f32 (K,N) row-major, staged to LDS as bf16.
// 256 threads = 4 waves stacked in m (32 rows each), 16x16x32 bf16 MFMA.
// A-frag: A[m=lane&15][k=quad*8+j]; B-frag: B[k=quad*8+j][n=lane&15];
// C/D: col=lane&15, row=quad*4+reg.
// ---------------------------------------------------------------------------
#define LDAB 40   // bf16 row stride in LDS (pad: 80B rows -> 2-way conflicts only)

__device__ __forceinline__ void gemm_core(
    const float* __restrict__ A, const float* __restrict__ W,
    const float* __restrict__ bias, const float* __restrict__ R,
    float* __restrict__ C, int M, int N, int K, int act,
    int bm, int bn, unsigned short* As, unsigned short* Bs)
{
    int tid = threadIdx.x, wave = tid >> 6, lane = tid & 63;
    int lm = lane & 15, quad = lane >> 4;

    f32x4 acc[2][4];
    #pragma unroll
    for (int i = 0; i < 2; ++i)
        #pragma unroll
        for (int j = 0; j < 4; ++j) acc[i][j] = (f32x4)(0.f);

    for (int k0 = 0; k0 < K; k0 += 32) {
        // stage A tile: 128 rows x 32 k (bf16), 512 8-elem items
        #pragma unroll
        for (int it = 0; it < 2; ++it) {
            int i = tid + it * 256;
            int m = i >> 2, kc = (i & 3) * 8;
            int gm = bm + m;
            float4 a0, a1;
            if (gm < M) {
                const float* p = A + (size_t)gm * K + k0 + kc;
                a0 = *(const float4*)p; a1 = *(const float4*)(p + 4);
            } else { a0 = make_float4(0,0,0,0); a1 = a0; }
            uint4 pk;
            pk.x = packbf2(a0.x, a0.y); pk.y = packbf2(a0.z, a0.w);
            pk.z = packbf2(a1.x, a1.y); pk.w = packbf2(a1.z, a1.w);
            *(uint4*)&As[m * LDAB + kc] = pk;
        }
        // stage B tile transposed: Bs[n][k], 64 n x 32 k
        {
            int nn = tid & 63, kq = (tid >> 6) * 8;
            const float* p = W + (size_t)(k0 + kq) * N + bn + nn;
            float w[8];
            #pragma unroll
            for (int j = 0; j < 8; ++j) w[j] = p[(size_t)j * N];
            uint4 pk;
            pk.x = packbf2(w[0], w[1]); pk.y = packbf2(w[2], w[3]);
            pk.z = packbf2(w[4], w[5]); pk.w = packbf2(w[6], w[7]);
            *(uint4*)&Bs[nn * LDAB + kq] = pk;
        }
        __syncthreads();
        bf16x8 af[2], bfr[4];
        #pragma unroll
        for (int mi = 0; mi < 2; ++mi)
            af[mi] = *(bf16x8*)&As[(wave * 32 + mi * 16 + lm) * LDAB + quad * 8];
        #pragma unroll
        for (int ni = 0; ni < 4; ++ni)
            bfr[ni] = *(bf16x8*)&Bs[(ni * 16 + lm) * LDAB + quad * 8];
        #pragma unroll
        for (int mi = 0; mi < 2; ++mi)
            #pragma unroll
            for (int ni = 0; ni < 4; ++ni)
                acc[mi][ni] = __builtin_amdgcn_mfma_f32_16x16x32_bf16(
                    af[mi], bfr[ni], acc[mi][ni], 0, 0, 0);
        __syncthreads();
    }
    #pragma unroll
    for (int mi = 0; mi < 2; ++mi) {
        #pragma unroll
        for (int r = 0; r < 4; ++r) {
            int row = bm + wave * 32 + mi * 16 + quad * 4 + r;
            if (row < M) {
                #pragma unroll
                for (int ni = 0; ni < 4; ++ni) {
                    int col = bn + ni * 16 + lm;
                    float v = acc[mi][ni][r] + bias[col];
                    if (R) v += R[(size_t)row * N + col];
                    if (act) v = fmaxf(v, 0.f);
                    C[(size_t)row * N + col] = v;
                }
            }
        }
    }
}

__global__ __launch_bounds__(256) void gemm_mfma(
    const float* __restrict__ A, const float* __restrict__ W,
    const float* __restrict__ bias, const float* __restrict__ R,
    float* __restrict__ C, int M, int N, int K, int act)
{
    __shared__ unsigned short As[128 * LDAB];
    __shared__ unsigned short Bs[64 * LDAB];
    gemm_core(A, W, bias, R, C, M, N, K, act,
              blockIdx.y * 128, blockIdx.x * 64, As, Bs);
}

// fused Q/K/V projection: grid.x = 6 (3 outputs x 2 n-halves)
__global__ __launch_bounds__(256) void qkv_mfma(
    const float* __restrict__ A,
    const float* __restrict__ wq, const float* __restrict__ wk, const float* __restrict__ wv,
    const float* __restrict__ bq, const float* __restrict__ bk, const float* __restrict__ bv,
    float* __restrict__ Q, float* __restrict__ Ko, float* __restrict__ V, int M, int D)
{
    __shared__ unsigned short As[128 * LDAB];
    __shared__ unsigned short Bs[64 * LDAB];
    int sel = blockIdx.x >> 1;
    const float* W = (sel == 0) ? wq : (sel == 1) ? wk : wv;
    const float* b = (sel == 0) ? bq : (sel == 1) ? bk : bv;
    float* C = (sel == 0) ? Q : (sel == 1) ? Ko : V;
    gemm_core(A, W, b, nullptr, C, M, D, D, 0,
              blockIdx.y * 128, (blockIdx.x & 1) * 64, As, Bs);
}

// ---------------------------------------------------------------------------
// Bi-interaction fused MFMA GEMM:
//   agg = leaky((ego+side)@W1+b1) + leaky((ego*side)@W2+b2), K=N=128
// ---------------------------------------------------------------------------
__global__ __launch_bounds__(256) void bi_gemm_mfma(
    const float* __restrict__ ego, const float* __restrict__ side,
    const float* __restrict__ W1, const float* __restrict__ b1,
    const float* __restrict__ W2, const float* __restrict__ b2,
    float* __restrict__ out, int M)
{
    __shared__ unsigned short Us[128 * LDAB];
    __shared__ unsigned short Ms[128 * LDAB];
    __shared__ unsigned short W1s[64 * LDAB];
    __shared__ unsigned short W2s[64 * LDAB];

    int tid = threadIdx.x, wave = tid >> 6, lane = tid & 63;
    int lm = lane & 15, quad = lane >> 4;
    int bm = blockIdx.y * 128, bn = blockIdx.x * 64;

    f32x4 acc1[2][4], acc2[2][4];
    #pragma unroll
    for (int i = 0; i < 2; ++i)
        #pragma unroll
        for (int j = 0; j < 4; ++j) { acc1[i][j] = (f32x4)(0.f); acc2[i][j] = (f32x4)(0.f); }

    for (int k0 = 0; k0 < 128; k0 += 32) {
        #pragma unroll
        for (int it = 0; it < 2; ++it) {
            int i = tid + it * 256;
            int m = i >> 2, kc = (i & 3) * 8;
            int gm = bm + m;
            float e[8], s[8];
            if (gm < M) {
                const float* pe = ego + (size_t)gm * 128 + k0 + kc;
                const float* ps = side + (size_t)gm * 128 + k0 + kc;
                float4 e0 = *(const float4*)pe, e1 = *(const float4*)(pe + 4);
                float4 s0 = *(const float4*)ps, s1 = *(const float4*)(ps + 4);
                e[0]=e0.x; e[1]=e0.y; e[2]=e0.z; e[3]=e0.w;
                e[4]=e1.x; e[5]=e1.y; e[6]=e1.z; e[7]=e1.w;
                s[0]=s0.x; s[1]=s0.y; s[2]=s0.z; s[3]=s0.w;
                s[4]=s1.x; s[5]=s1.y; s[6]=s1.z; s[7]=s1.w;
            } else {
                #pragma unroll
                for (int j = 0; j < 8; ++j) { e[j] = 0.f; s[j] = 0.f; }
            }
            uint4 pu, pm;
            pu.x = packbf2(e[0]+s[0], e[1]+s[1]); pu.y = packbf2(e[2]+s[2], e[3]+s[3]);
            pu.z = packbf2(e[4]+s[4], e[5]+s[5]); pu.w = packbf2(e[6]+s[6], e[7]+s[7]);
            pm.x = packbf2(e[0]*s[0], e[1]*s[1]); pm.y = packbf2(e[2]*s[2], e[3]*s[3]);
            pm.z = packbf2(e[4]*s[4], e[5]*s[5]); pm.w = packbf2(e[6]*s[6], e[7]*s[7]);
            *(uint4*)&Us[m * LDAB + kc] = pu;
            *(uint4*)&Ms[m * LDAB + kc] = pm;
        }
        {
            int nn = tid & 63, kq = (tid >> 6) * 8;
            const float* p1 = W1 + (size_t)(k0 + kq) * 128 + bn + nn;
            const float* p2 = W2 + (size_t)(k0 + kq) * 128 + bn + nn;
            float wa[8], wb[8];
            #pragma unroll
            for (int j = 0; j < 8; ++j) { wa[j] = p1[(size_t)j * 128]; wb[j] = p2[(size_t)j * 128]; }
            uint4 pk1, pk2;
            pk1.x = packbf2(wa[0],wa[1]); pk1.y = packbf2(wa[2],wa[3]);
            pk1.z = packbf2(wa[4],wa[5]); pk1.w = packbf2(wa[6],wa[7]);
            pk2.x = packbf2(wb[0],wb[1]); pk2.y = packbf2(wb[2],wb[3]);
            pk2.z = packbf2(wb[4],wb[5]); pk2.w = packbf2(wb[6],wb[7]);
            *(uint4*)&W1s[nn * LDAB + kq] = pk1;
            *(uint4*)&W2s[nn * LDAB + kq] = pk2;
        }
        __syncthreads();
        bf16x8 au[2], am[2], bf1[4], bf2[4];
        #pragma unroll
        for (int mi = 0; mi < 2; ++mi) {
            au[mi] = *(bf16x8*)&Us[(wave * 32 + mi * 16 + lm) * LDAB + quad * 8];
            am[mi] = *(bf16x8*)&Ms[(wave * 32 + mi * 16 + lm) * LDAB + quad * 8];
        }
        #pragma unroll
        for (int ni = 0; ni < 4; ++ni) {
            bf1[ni] = *(bf16x8*)&W1s[(ni * 16 + lm) * LDAB + quad * 8];
            bf2[ni] = *(bf16x8*)&W2s[(ni * 16 + lm) * LDAB + quad * 8];
        }
        #pragma unroll
        for (int mi = 0; mi < 2; ++mi)
            #pragma unroll
            for (int ni = 0; ni < 4; ++ni) {
                acc1[mi][ni] = __builtin_amdgcn_mfma_f32_16x16x32_bf16(
                    au[mi], bf1[ni], acc1[mi][ni], 0, 0, 0);
                acc2[mi][ni] = __builtin_amdgcn_mfma_f32_16x16x32_bf16(
                    am[mi], bf2[ni], acc2[mi][ni], 0, 0, 0);
            }
        __syncthreads();
    }
    #pragma unroll
    for (int mi = 0; mi < 2; ++mi) {
        #pragma unroll
        for (int r = 0; r < 4; ++r) {
            int row = bm + wave * 32 + mi * 16 + quad * 4 + r;
            if (row < M) {
                #pragma unroll
                for (int ni = 0; ni < 4; ++ni) {
                    int col = bn + ni * 16 + lm;
                    float v1 = acc1[mi][ni][r] + b1[col];
                    v1 = v1 > 0.f ? v1 : 0.01f * v1;
                    float v2 = acc2[mi][ni][r] + b2[col];
                    v2 = v2 > 0.f ? v2 : 0.01f * v2;
                    out[(size_t)row * 128 + col] = v1 + v2;
                }
            }
        }
    }
}

// ---------------------------------------------------------------------------
// Attention: block = (b, h, half of queries), 128 threads, single-pass
// online softmax. L == 256, DK == 16.
// ---------------------------------------------------------------------------
__global__ __launch_bounds__(128) void attn_kernel(
    const float* __restrict__ q, const float* __restrict__ k,
    const float* __restrict__ v, float* __restrict__ o, int NH)
{
    const int L = 256, DK = 16;
    __shared__ float Ks[L * DK];
    __shared__ float Vs[L * DK];
    int bh = blockIdx.x >> 1;
    int half = blockIdx.x & 1;
    int b = bh / NH, h = bh % NH;
    int tid = threadIdx.x;

    for (int i = tid; i < L * 4; i += 128) {
        int l = i >> 2, d4 = (i & 3) * 4;
        size_t g = ((size_t)(b * L + l) * NH + h) * DK + d4;
        *(float4*)&Ks[l * 16 + d4] = *(const float4*)(k + g);
        *(float4*)&Vs[l * 16 + d4] = *(const float4*)(v + g);
    }
    __syncthreads();

    int l = half * 128 + tid;
    size_t qbase = ((size_t)(b * L + l) * NH + h) * DK;
    float qr[16];
    #pragma unroll
    for (int d4 = 0; d4 < 4; ++d4) {
        float4 t = *(const float4*)(q + qbase + d4 * 4);
        qr[d4*4+0] = t.x * 0.25f; qr[d4*4+1] = t.y * 0.25f;
        qr[d4*4+2] = t.z * 0.25f; qr[d4*4+3] = t.w * 0.25f;
    }
    float acc[16];
    #pragma unroll
    for (int d = 0; d < 16; ++d) acc[d] = 0.f;
    float mmax = -1e30f, ssum = 0.f;
    for (int kk = 0; kk < L; ++kk) {
        float dot = 0.f;
        #pragma unroll
        for (int d4 = 0; d4 < 4; ++d4) {
            float4 kv = *(const float4*)&Ks[kk * 16 + d4 * 4];
            dot = fmaf(qr[d4*4+0], kv.x, dot);
            dot = fmaf(qr[d4*4+1], kv.y, dot);
            dot = fmaf(qr[d4*4+2], kv.z, dot);
            dot = fmaf(qr[d4*4+3], kv.w, dot);
        }
        if (dot > mmax) {
            float alpha = __expf(mmax - dot);
            ssum *= alpha;
            #pragma unroll
            for (int d = 0; d < 16; ++d) acc[d] *= alpha;
            mmax = dot;
        }
        float p = __expf(dot - mmax);
        ssum += p;
        #pragma unroll
        for (int d4 = 0; d4 < 4; ++d4) {
            float4 vv = *(const float4*)&Vs[kk * 16 + d4 * 4];
            acc[d4*4+0] = fmaf(p, vv.x, acc[d4*4+0]);
            acc[d4*4+1] = fmaf(p, vv.y, acc[d4*4+1]);
            acc[d4*4+2] = fmaf(p, vv.z, acc[d4*4+2]);
            acc[d4*4+3] = fmaf(p, vv.w, acc[d4*4+3]);
        }
    }
    float inv = 1.f / ssum;
    #pragma unroll
    for (int d4 = 0; d4 < 4; ++d4) {
        float4 t;
        t.x = acc[d4*4+0] * inv; t.y = acc[d4*4+1] * inv;
        t.z = acc[d4*4+2] * inv; t.w = acc[d4*4+3] * inv;
        *(float4*)(o + qbase + d4 * 4) = t;
    }
}

// ---------------------------------------------------------------------------
// LayerNorm over rows of 128. One wave per row (2 elems/lane).
// ---------------------------------------------------------------------------
__global__ __launch_bounds__(256) void ln_kernel(
    const float* __restrict__ X, const float* __restrict__ g,
    const float* __restrict__ b, float* __restrict__ outF, int Mrows)
{
    int wave = threadIdx.x >> 6;
    int lane = threadIdx.x & 63;
    int r = blockIdx.x * 4 + wave;
    if (r >= Mrows) return;

    float2 x2 = *(const float2*)(X + (size_t)r * 128 + lane * 2);
    float s = x2.x + x2.y;
    float ss = x2.x * x2.x + x2.y * x2.y;
    #pragma unroll
    for (int off = 32; off > 0; off >>= 1) {
        s  += __shfl_xor(s, off, 64);
        ss += __shfl_xor(ss, off, 64);
    }
    float mean = s * (1.f / 128.f);
    float var = ss * (1.f / 128.f) - mean * mean;
    float rstd = rsqrtf(var + 1e-5f);
    float y0 = (x2.x - mean) * rstd * g[lane * 2 + 0] + b[lane * 2 + 0];
    float y1 = (x2.y - mean) * rstd * g[lane * 2 + 1] + b[lane * 2 + 1];
    *(float2*)(outF + (size_t)r * 128 + lane * 2) = make_float2(y0, y1);
}

extern "C" void kernel_launch(void* const* d_in, const int* in_sizes, int n_in,
                              void* d_out, int out_size, void* d_ws, size_t ws_size,
                              hipStream_t stream) {
    const float* ego    = (const float*)d_in[0];
    const float* vals   = (const float*)d_in[1];
    const float* W1     = (const float*)d_in[2];
    const float* b1     = (const float*)d_in[3];
    const float* W2     = (const float*)d_in[4];
    const float* b2     = (const float*)d_in[5];
    const float* enc_in = (const float*)d_in[6];
    const float* wq  = (const float*)d_in[7];
    const float* bq  = (const float*)d_in[8];
    const float* wk  = (const float*)d_in[9];
    const float* bk  = (const float*)d_in[10];
    const float* wv  = (const float*)d_in[11];
    const float* bv  = (const float*)d_in[12];
    const float* wo  = (const float*)d_in[13];
    const float* bo  = (const float*)d_in[14];
    const float* ln1_g = (const float*)d_in[15];
    const float* ln1_b = (const float*)d_in[16];
    const float* cw1 = (const float*)d_in[17];
    const float* cb1 = (const float*)d_in[18];
    const float* cw2 = (const float*)d_in[19];
    const float* cb2 = (const float*)d_in[20];
    const float* ln2_g = (const float*)d_in[21];
    const float* ln2_b = (const float*)d_in[22];
    const int* rows = (const int*)d_in[23];
    const int* cols = (const int*)d_in[24];

    const int D = 128, DI = 512, NH = 8, L = 256;
    const int Nn   = in_sizes[0] / D;        // 100000
    const int nnz  = in_sizes[1];            // 2000000
    const int NL   = in_sizes[7] / (D * D);  // 2
    const int Menc = in_sizes[6] / D;        // 8192 (= B*L)
    const int Bb   = Menc / L;               // 32

    float* ws = (float*)d_ws;
    size_t off = 0;
    float* side = ws + off; off += (size_t)Nn * D;
    float* Qb = ws + off; off += (size_t)Menc * D;
    float* Kb = ws + off; off += (size_t)Menc * D;
    float* Vb = ws + off; off += (size_t)Menc * D;
    float* Ob = ws + off; off += (size_t)Menc * D;
    float* Tb = ws + off; off += (size_t)Menc * D;
    float* XA = ws + off; off += (size_t)Menc * D;
    float* XB = ws + off; off += (size_t)Menc * D;
    float* Hb = ws + off; off += (size_t)Menc * DI;
    unsigned int* egob = (unsigned int*)(ws + off); off += (size_t)Nn * (D / 2); // bf16 copy of ego

    float* outAgg = (float*)d_out;
    float* outX   = (float*)d_out + (size_t)Nn * D;

    // ---- Part A: SpMM + bi-interaction ----
    hipMemsetAsync(side, 0, (size_t)Nn * D * sizeof(float), stream);
    ego2bf16_kernel<<<2048, 256, 0, stream>>>(ego, egob, (size_t)Nn * (D / 4));
    spmm_kernel<<<(nnz + 255) / 256, 256, 0, stream>>>(egob, vals, rows, cols, side, nnz);
    bi_gemm_mfma<<<dim3(2, (Nn + 127) / 128), 256, 0, stream>>>(
        ego, side, W1, b1, W2, b2, outAgg, Nn);

    // ---- Part B: transformer encoder ----
    const float* x = enc_in;
    for (int i = 0; i < NL; ++i) {
        const size_t wOff = (size_t)i * D * D;
        qkv_mfma<<<dim3(6, Menc / 128), 256, 0, stream>>>(
            x, wq + wOff, wk + wOff, wv + wOff,
            bq + (size_t)i * D, bk + (size_t)i * D, bv + (size_t)i * D,
            Qb, Kb, Vb, Menc, D);
        attn_kernel<<<Bb * NH * 2, 128, 0, stream>>>(Qb, Kb, Vb, Ob, NH);
        gemm_mfma<<<dim3(2, Menc / 128), 256, 0, stream>>>(
            Ob, wo + wOff, bo + (size_t)i * D, x, Tb, Menc, D, D, 0);
        ln_kernel<<<Menc / 4, 256, 0, stream>>>(
            Tb, ln1_g + (size_t)i * D, ln1_b + (size_t)i * D, XA, Menc);
        gemm_mfma<<<dim3(DI / 64, Menc / 128), 256, 0, stream>>>(
            XA, cw1 + (size_t)i * D * DI, cb1 + (size_t)i * DI, nullptr, Hb, Menc, DI, D, 1);
        gemm_mfma<<<dim3(2, Menc / 128), 256, 0, stream>>>(
            Hb, cw2 + (size_t)i * DI * D, cb2 + (size_t)i * D, XA, Tb, Menc, D, DI, 0);
        if (i == NL - 1) {
            ln_kernel<<<Menc / 4, 256, 0, stream>>>(
                Tb, ln2_g + (size_t)i * D, ln2_b + (size_t)i * D, outX, Menc);
        } else {
            ln_kernel<<<Menc / 4, 256, 0, stream>>>(
                Tb, ln2_g + (size_t)i * D, ln2_b + (size_t)i * D, XB, Menc);
            x = XB;
        }
    }
}

// Round 2
// 608.197 us; speedup vs baseline: 1.0645x; 1.0421x over previous
//
#include <hip/hip_runtime.h>

typedef __attribute__((ext_vector_type(8))) short bf16x8;
typedef __attribute__((ext_vector_type(4))) float f32x4;

__device__ __forceinline__ unsigned short f2b(float f) {
    union { float f; unsigned int i; } u; u.f = f;
    return (unsigned short)((u.i + 0x7FFFu + ((u.i >> 16) & 1u)) >> 16);
}
__device__ __forceinline__ unsigned int packbf2(float a, float b) {
    return (unsigned int)f2b(a) | ((unsigned int)f2b(b) << 16);
}

// ---------------------------------------------------------------------------
// ego -> bf16 copy (packed 2/uint). Streaming, grid-stride.
// ---------------------------------------------------------------------------
__global__ __launch_bounds__(256) void ego2bf16_kernel(
    const float* __restrict__ ego, unsigned int* __restrict__ egob, size_t n4)
{
    size_t i = (size_t)blockIdx.x * 256 + threadIdx.x;
    size_t stride = (size_t)gridDim.x * 256;
    for (; i < n4; i += stride) {
        float4 a = *(const float4*)(ego + i * 4);
        uint2 p;
        p.x = packbf2(a.x, a.y);
        p.y = packbf2(a.z, a.w);
        *(uint2*)(egob + i * 2) = p;
    }
}

// ---------------------------------------------------------------------------
// SpMM: side[r,:] += vals[e] * ego_bf16[cols[e],:]  (rows sorted).
// Block = 256 threads = 4 independent waves; each wave owns 64 edges; lane
// holds 2 columns packed in one dword (bf16x2).
// Per-edge metadata (row/col/val) is wave-uniform: lane i loads edge i's
// metadata once (coalesced), then the fully-unrolled 64-edge loop broadcasts
// it with v_readlane into SGPRs. Row-transition test is a scalar branch;
// gather uses a uniform (SGPR) row base + constant lane*4 vaddr (saddr form).
// Tail waves clamp to the last edge with val=0 (contributes nothing), so the
// loop has no bounds checks at all. Depth-16 register prefetch queue.
// ---------------------------------------------------------------------------
__global__ __launch_bounds__(256) void spmm_kernel(
    const unsigned int* __restrict__ egob, const float* __restrict__ vals,
    const int* __restrict__ rows, const int* __restrict__ cols,
    float* __restrict__ side, int nnz)
{
    int tid = threadIdx.x;
    int wave = tid >> 6, lane = tid & 63;
    int e0 = blockIdx.x * 256 + wave * 64;
    if (e0 >= nnz) return;

    int idx = e0 + lane;
    int last = nnz - 1;
    bool ok = idx < nnz;
    int safe = ok ? idx : last;
    int my_row = rows[safe];
    int my_col = cols[safe];
    float my_val = ok ? vals[safe] : 0.f;

    unsigned int pre[16];
    #pragma unroll
    for (int j = 0; j < 16; ++j) {
        unsigned int c = (unsigned int)__builtin_amdgcn_readlane(my_col, j);
        pre[j] = *(egob + ((size_t)c << 6) + lane);
    }

    float ax = 0.f, ay = 0.f;
    int cur = __builtin_amdgcn_readlane(my_row, 0);
    #pragma unroll
    for (int e = 0; e < 64; ++e) {
        int r = __builtin_amdgcn_readlane(my_row, e);
        float vv = __int_as_float(__builtin_amdgcn_readlane(__float_as_int(my_val), e));
        unsigned int u = pre[e & 15];
        if (e < 48) {
            unsigned int c = (unsigned int)__builtin_amdgcn_readlane(my_col, e + 16);
            pre[e & 15] = *(egob + ((size_t)c << 6) + lane);
        }
        if (r != cur) {
            atomicAdd(&side[(size_t)cur * 128 + lane * 2], ax);
            atomicAdd(&side[(size_t)cur * 128 + lane * 2 + 1], ay);
            ax = 0.f; ay = 0.f; cur = r;
        }
        ax = fmaf(vv, __uint_as_float(u << 16), ax);
        ay = fmaf(vv, __uint_as_float(u & 0xFFFF0000u), ay);
    }
    atomicAdd(&side[(size_t)cur * 128 + lane * 2], ax);
    atomicAdd(&side[(size_t)cur * 128 + lane * 2 + 1], ay);
}

// ---------------------------------------------------------------------------
// MFMA GEMM core: C[bm:bm+128, bn:bn+64] = act(A@W + bias [+R]).
// A f32 (M,K) row-major, W f32 (K,N) row-major, staged to LDS as bf16.
// 256 threads = 4 waves stacked in m (32 rows each), 16x16x32 bf16 MFMA.
// A-frag: A[m=lane&15][k=quad*8+j]; B-frag: B[k=quad*8+j][n=lane&15];
// C/D: col=lane&15, row=quad*4+reg.
// ---------------------------------------------------------------------------
#define LDAB 40   // bf16 row stride in LDS (pad: 80B rows -> 2-way conflicts only)

__device__ __forceinline__ void gemm_core(
    const float* __restrict__ A, const float* __restrict__ W,
    const float* __restrict__ bias, const float* __restrict__ R,
    float* __restrict__ C, int M, int N, int K, int act,
    int bm, int bn, unsigned short* As, unsigned short* Bs)
{
    int tid = threadIdx.x, wave = tid >> 6, lane = tid & 63;
    int lm = lane & 15, quad = lane >> 4;

    f32x4 acc[2][4];
    #pragma unroll
    for (int i = 0; i < 2; ++i)
        #pragma unroll
        for (int j = 0; j < 4; ++j) acc[i][j] = (f32x4)(0.f);

    for (int k0 = 0; k0 < K; k0 += 32) {
        // stage A tile: 128 rows x 32 k (bf16), 512 8-elem items
        #pragma unroll
        for (int it = 0; it < 2; ++it) {
            int i = tid + it * 256;
            int m = i >> 2, kc = (i & 3) * 8;
            int gm = bm + m;
            float4 a0, a1;
            if (gm < M) {
                const float* p = A + (size_t)gm * K + k0 + kc;
                a0 = *(const float4*)p; a1 = *(const float4*)(p + 4);
            } else { a0 = make_float4(0,0,0,0); a1 = a0; }
            uint4 pk;
            pk.x = packbf2(a0.x, a0.y); pk.y = packbf2(a0.z, a0.w);
            pk.z = packbf2(a1.x, a1.y); pk.w = packbf2(a1.z, a1.w);
            *(uint4*)&As[m * LDAB + kc] = pk;
        }
        // stage B tile transposed: Bs[n][k], 64 n x 32 k
        {
            int nn = tid & 63, kq = (tid >> 6) * 8;
            const float* p = W + (size_t)(k0 + kq) * N + bn + nn;
            float w[8];
            #pragma unroll
            for (int j = 0; j < 8; ++j) w[j] = p[(size_t)j * N];
            uint4 pk;
            pk.x = packbf2(w[0], w[1]); pk.y = packbf2(w[2], w[3]);
            pk.z = packbf2(w[4], w[5]); pk.w = packbf2(w[6], w[7]);
            *(uint4*)&Bs[nn * LDAB + kq] = pk;
        }
        __syncthreads();
        bf16x8 af[2], bfr[4];
        #pragma unroll
        for (int mi = 0; mi < 2; ++mi)
            af[mi] = *(bf16x8*)&As[(wave * 32 + mi * 16 + lm) * LDAB + quad * 8];
        #pragma unroll
        for (int ni = 0; ni < 4; ++ni)
            bfr[ni] = *(bf16x8*)&Bs[(ni * 16 + lm) * LDAB + quad * 8];
        #pragma unroll
        for (int mi = 0; mi < 2; ++mi)
            #pragma unroll
            for (int ni = 0; ni < 4; ++ni)
                acc[mi][ni] = __builtin_amdgcn_mfma_f32_16x16x32_bf16(
                    af[mi], bfr[ni], acc[mi][ni], 0, 0, 0);
        __syncthreads();
    }
    #pragma unroll
    for (int mi = 0; mi < 2; ++mi) {
        #pragma unroll
        for (int r = 0; r < 4; ++r) {
            int row = bm + wave * 32 + mi * 16 + quad * 4 + r;
            if (row < M) {
                #pragma unroll
                for (int ni = 0; ni < 4; ++ni) {
                    int col = bn + ni * 16 + lm;
                    float v = acc[mi][ni][r] + bias[col];
                    if (R) v += R[(size_t)row * N + col];
                    if (act) v = fmaxf(v, 0.f);
                    C[(size_t)row * N + col] = v;
                }
            }
        }
    }
}

__global__ __launch_bounds__(256) void gemm_mfma(
    const float* __restrict__ A, const float* __restrict__ W,
    const float* __restrict__ bias, const float* __restrict__ R,
    float* __restrict__ C, int M, int N, int K, int act)
{
    __shared__ unsigned short As[128 * LDAB];
    __shared__ unsigned short Bs[64 * LDAB];
    gemm_core(A, W, bias, R, C, M, N, K, act,
              blockIdx.y * 128, blockIdx.x * 64, As, Bs);
}

// fused Q/K/V projection: grid.x = 6 (3 outputs x 2 n-halves)
__global__ __launch_bounds__(256) void qkv_mfma(
    const float* __restrict__ A,
    const float* __restrict__ wq, const float* __restrict__ wk, const float* __restrict__ wv,
    const float* __restrict__ bq, const float* __restrict__ bk, const float* __restrict__ bv,
    float* __restrict__ Q, float* __restrict__ Ko, float* __restrict__ V, int M, int D)
{
    __shared__ unsigned short As[128 * LDAB];
    __shared__ unsigned short Bs[64 * LDAB];
    int sel = blockIdx.x >> 1;
    const float* W = (sel == 0) ? wq : (sel == 1) ? wk : wv;
    const float* b = (sel == 0) ? bq : (sel == 1) ? bk : bv;
    float* C = (sel == 0) ? Q : (sel == 1) ? Ko : V;
    gemm_core(A, W, b, nullptr, C, M, D, D, 0,
              blockIdx.y * 128, (blockIdx.x & 1) * 64, As, Bs);
}

// ---------------------------------------------------------------------------
// Bi-interaction fused MFMA GEMM:
//   agg = leaky((ego+side)@W1+b1) + leaky((ego*side)@W2+b2), K=N=128
// ---------------------------------------------------------------------------
__global__ __launch_bounds__(256) void bi_gemm_mfma(
    const float* __restrict__ ego, const float* __restrict__ side,
    const float* __restrict__ W1, const float* __restrict__ b1,
    const float* __restrict__ W2, const float* __restrict__ b2,
    float* __restrict__ out, int M)
{
    __shared__ unsigned short Us[128 * LDAB];
    __shared__ unsigned short Ms[128 * LDAB];
    __shared__ unsigned short W1s[64 * LDAB];
    __shared__ unsigned short W2s[64 * LDAB];

    int tid = threadIdx.x, wave = tid >> 6, lane = tid & 63;
    int lm = lane & 15, quad = lane >> 4;
    int bm = blockIdx.y * 128, bn = blockIdx.x * 64;

    f32x4 acc1[2][4], acc2[2][4];
    #pragma unroll
    for (int i = 0; i < 2; ++i)
        #pragma unroll
        for (int j = 0; j < 4; ++j) { acc1[i][j] = (f32x4)(0.f); acc2[i][j] = (f32x4)(0.f); }

    for (int k0 = 0; k0 < 128; k0 += 32) {
        #pragma unroll
        for (int it = 0; it < 2; ++it) {
            int i = tid + it * 256;
            int m = i >> 2, kc = (i & 3) * 8;
            int gm = bm + m;
            float e[8], s[8];
            if (gm < M) {
                const float* pe = ego + (size_t)gm * 128 + k0 + kc;
                const float* ps = side + (size_t)gm * 128 + k0 + kc;
                float4 e0 = *(const float4*)pe, e1 = *(const float4*)(pe + 4);
                float4 s0 = *(const float4*)ps, s1 = *(const float4*)(ps + 4);
                e[0]=e0.x; e[1]=e0.y; e[2]=e0.z; e[3]=e0.w;
                e[4]=e1.x; e[5]=e1.y; e[6]=e1.z; e[7]=e1.w;
                s[0]=s0.x; s[1]=s0.y; s[2]=s0.z; s[3]=s0.w;
                s[4]=s1.x; s[5]=s1.y; s[6]=s1.z; s[7]=s1.w;
            } else {
                #pragma unroll
                for (int j = 0; j < 8; ++j) { e[j] = 0.f; s[j] = 0.f; }
            }
            uint4 pu, pm;
            pu.x = packbf2(e[0]+s[0], e[1]+s[1]); pu.y = packbf2(e[2]+s[2], e[3]+s[3]);
            pu.z = packbf2(e[4]+s[4], e[5]+s[5]); pu.w = packbf2(e[6]+s[6], e[7]+s[7]);
            pm.x = packbf2(e[0]*s[0], e[1]*s[1]); pm.y = packbf2(e[2]*s[2], e[3]*s[3]);
            pm.z = packbf2(e[4]*s[4], e[5]*s[5]); pm.w = packbf2(e[6]*s[6], e[7]*s[7]);
            *(uint4*)&Us[m * LDAB + kc] = pu;
            *(uint4*)&Ms[m * LDAB + kc] = pm;
        }
        {
            int nn = tid & 63, kq = (tid >> 6) * 8;
            const float* p1 = W1 + (size_t)(k0 + kq) * 128 + bn + nn;
            const float* p2 = W2 + (size_t)(k0 + kq) * 128 + bn + nn;
            float wa[8], wb[8];
            #pragma unroll
            for (int j = 0; j < 8; ++j) { wa[j] = p1[(size_t)j * 128]; wb[j] = p2[(size_t)j * 128]; }
            uint4 pk1, pk2;
            pk1.x = packbf2(wa[0],wa[1]); pk1.y = packbf2(wa[2],wa[3]);
            pk1.z = packbf2(wa[4],wa[5]); pk1.w = packbf2(wa[6],wa[7]);
            pk2.x = packbf2(wb[0],wb[1]); pk2.y = packbf2(wb[2],wb[3]);
            pk2.z = packbf2(wb[4],wb[5]); pk2.w = packbf2(wb[6],wb[7]);
            *(uint4*)&W1s[nn * LDAB + kq] = pk1;
            *(uint4*)&W2s[nn * LDAB + kq] = pk2;
        }
        __syncthreads();
        bf16x8 au[2], am[2], bf1[4], bf2[4];
        #pragma unroll
        for (int mi = 0; mi < 2; ++mi) {
            au[mi] = *(bf16x8*)&Us[(wave * 32 + mi * 16 + lm) * LDAB + quad * 8];
            am[mi] = *(bf16x8*)&Ms[(wave * 32 + mi * 16 + lm) * LDAB + quad * 8];
        }
        #pragma unroll
        for (int ni = 0; ni < 4; ++ni) {
            bf1[ni] = *(bf16x8*)&W1s[(ni * 16 + lm) * LDAB + quad * 8];
            bf2[ni] = *(bf16x8*)&W2s[(ni * 16 + lm) * LDAB + quad * 8];
        }
        #pragma unroll
        for (int mi = 0; mi < 2; ++mi)
            #pragma unroll
            for (int ni = 0; ni < 4; ++ni) {
                acc1[mi][ni] = __builtin_amdgcn_mfma_f32_16x16x32_bf16(
                    au[mi], bf1[ni], acc1[mi][ni], 0, 0, 0);
                acc2[mi][ni] = __builtin_amdgcn_mfma_f32_16x16x32_bf16(
                    am[mi], bf2[ni], acc2[mi][ni], 0, 0, 0);
            }
        __syncthreads();
    }
    #pragma unroll
    for (int mi = 0; mi < 2; ++mi) {
        #pragma unroll
        for (int r = 0; r < 4; ++r) {
            int row = bm + wave * 32 + mi * 16 + quad * 4 + r;
            if (row < M) {
                #pragma unroll
                for (int ni = 0; ni < 4; ++ni) {
                    int col = bn + ni * 16 + lm;
                    float v1 = acc1[mi][ni][r] + b1[col];
                    v1 = v1 > 0.f ? v1 : 0.01f * v1;
                    float v2 = acc2[mi][ni][r] + b2[col];
                    v2 = v2 > 0.f ? v2 : 0.01f * v2;
                    out[(size_t)row * 128 + col] = v1 + v2;
                }
            }
        }
    }
}

// ---------------------------------------------------------------------------
// Attention: block = (b, h, half of queries), 128 threads, single-pass
// online softmax. L == 256, DK == 16.
// ---------------------------------------------------------------------------
__global__ __launch_bounds__(128) void attn_kernel(
    const float* __restrict__ q, const float* __restrict__ k,
    const float* __restrict__ v, float* __restrict__ o, int NH)
{
    const int L = 256, DK = 16;
    __shared__ float Ks[L * DK];
    __shared__ float Vs[L * DK];
    int bh = blockIdx.x >> 1;
    int half = blockIdx.x & 1;
    int b = bh / NH, h = bh % NH;
    int tid = threadIdx.x;

    for (int i = tid; i < L * 4; i += 128) {
        int l = i >> 2, d4 = (i & 3) * 4;
        size_t g = ((size_t)(b * L + l) * NH + h) * DK + d4;
        *(float4*)&Ks[l * 16 + d4] = *(const float4*)(k + g);
        *(float4*)&Vs[l * 16 + d4] = *(const float4*)(v + g);
    }
    __syncthreads();

    int l = half * 128 + tid;
    size_t qbase = ((size_t)(b * L + l) * NH + h) * DK;
    float qr[16];
    #pragma unroll
    for (int d4 = 0; d4 < 4; ++d4) {
        float4 t = *(const float4*)(q + qbase + d4 * 4);
        qr[d4*4+0] = t.x * 0.25f; qr[d4*4+1] = t.y * 0.25f;
        qr[d4*4+2] = t.z * 0.25f; qr[d4*4+3] = t.w * 0.25f;
    }
    float acc[16];
    #pragma unroll
    for (int d = 0; d < 16; ++d) acc[d] = 0.f;
    float mmax = -1e30f, ssum = 0.f;
    for (int kk = 0; kk < L; ++kk) {
        float dot = 0.f;
        #pragma unroll
        for (int d4 = 0; d4 < 4; ++d4) {
            float4 kv = *(const float4*)&Ks[kk * 16 + d4 * 4];
            dot = fmaf(qr[d4*4+0], kv.x, dot);
            dot = fmaf(qr[d4*4+1], kv.y, dot);
            dot = fmaf(qr[d4*4+2], kv.z, dot);
            dot = fmaf(qr[d4*4+3], kv.w, dot);
        }
        if (dot > mmax) {
            float alpha = __expf(mmax - dot);
            ssum *= alpha;
            #pragma unroll
            for (int d = 0; d < 16; ++d) acc[d] *= alpha;
            mmax = dot;
        }
        float p = __expf(dot - mmax);
        ssum += p;
        #pragma unroll
        for (int d4 = 0; d4 < 4; ++d4) {
            float4 vv = *(const float4*)&Vs[kk * 16 + d4 * 4];
            acc[d4*4+0] = fmaf(p, vv.x, acc[d4*4+0]);
            acc[d4*4+1] = fmaf(p, vv.y, acc[d4*4+1]);
            acc[d4*4+2] = fmaf(p, vv.z, acc[d4*4+2]);
            acc[d4*4+3] = fmaf(p, vv.w, acc[d4*4+3]);
        }
    }
    float inv = 1.f / ssum;
    #pragma unroll
    for (int d4 = 0; d4 < 4; ++d4) {
        float4 t;
        t.x = acc[d4*4+0] * inv; t.y = acc[d4*4+1] * inv;
        t.z = acc[d4*4+2] * inv; t.w = acc[d4*4+3] * inv;
        *(float4*)(o + qbase + d4 * 4) = t;
    }
}

// ---------------------------------------------------------------------------
// LayerNorm over rows of 128. One wave per row (2 elems/lane).
// ---------------------------------------------------------------------------
__global__ __launch_bounds__(256) void ln_kernel(
    const float* __restrict__ X, const float* __restrict__ g,
    const float* __restrict__ b, float* __restrict__ outF, int Mrows)
{
    int wave = threadIdx.x >> 6;
    int lane = threadIdx.x & 63;
    int r = blockIdx.x * 4 + wave;
    if (r >= Mrows) return;

    float2 x2 = *(const float2*)(X + (size_t)r * 128 + lane * 2);
    float s = x2.x + x2.y;
    float ss = x2.x * x2.x + x2.y * x2.y;
    #pragma unroll
    for (int off = 32; off > 0; off >>= 1) {
        s  += __shfl_xor(s, off, 64);
        ss += __shfl_xor(ss, off, 64);
    }
    float mean = s * (1.f / 128.f);
    float var = ss * (1.f / 128.f) - mean * mean;
    float rstd = rsqrtf(var + 1e-5f);
    float y0 = (x2.x - mean) * rstd * g[lane * 2 + 0] + b[lane * 2 + 0];
    float y1 = (x2.y - mean) * rstd * g[lane * 2 + 1] + b[lane * 2 + 1];
    *(float2*)(outF + (size_t)r * 128 + lane * 2) = make_float2(y0, y1);
}

extern "C" void kernel_launch(void* const* d_in, const int* in_sizes, int n_in,
                              void* d_out, int out_size, void* d_ws, size_t ws_size,
                              hipStream_t stream) {
    const float* ego    = (const float*)d_in[0];
    const float* vals   = (const float*)d_in[1];
    const float* W1     = (const float*)d_in[2];
    const float* b1     = (const float*)d_in[3];
    const float* W2     = (const float*)d_in[4];
    const float* b2     = (const float*)d_in[5];
    const float* enc_in = (const float*)d_in[6];
    const float* wq  = (const float*)d_in[7];
    const float* bq  = (const float*)d_in[8];
    const float* wk  = (const float*)d_in[9];
    const float* bk  = (const float*)d_in[10];
    const float* wv  = (const float*)d_in[11];
    const float* bv  = (const float*)d_in[12];
    const float* wo  = (const float*)d_in[13];
    const float* bo  = (const float*)d_in[14];
    const float* ln1_g = (const float*)d_in[15];
    const float* ln1_b = (const float*)d_in[16];
    const float* cw1 = (const float*)d_in[17];
    const float* cb1 = (const float*)d_in[18];
    const float* cw2 = (const float*)d_in[19];
    const float* cb2 = (const float*)d_in[20];
    const float* ln2_g = (const float*)d_in[21];
    const float* ln2_b = (const float*)d_in[22];
    const int* rows = (const int*)d_in[23];
    const int* cols = (const int*)d_in[24];

    const int D = 128, DI = 512, NH = 8, L = 256;
    const int Nn   = in_sizes[0] / D;        // 100000
    const int nnz  = in_sizes[1];            // 2000000
    const int NL   = in_sizes[7] / (D * D);  // 2
    const int Menc = in_sizes[6] / D;        // 8192 (= B*L)
    const int Bb   = Menc / L;               // 32

    float* ws = (float*)d_ws;
    size_t off = 0;
    float* side = ws + off; off += (size_t)Nn * D;
    float* Qb = ws + off; off += (size_t)Menc * D;
    float* Kb = ws + off; off += (size_t)Menc * D;
    float* Vb = ws + off; off += (size_t)Menc * D;
    float* Ob = ws + off; off += (size_t)Menc * D;
    float* Tb = ws + off; off += (size_t)Menc * D;
    float* XA = ws + off; off += (size_t)Menc * D;
    float* XB = ws + off; off += (size_t)Menc * D;
    float* Hb = ws + off; off += (size_t)Menc * DI;
    unsigned int* egob = (unsigned int*)(ws + off); off += (size_t)Nn * (D / 2); // bf16 copy of ego

    float* outAgg = (float*)d_out;
    float* outX   = (float*)d_out + (size_t)Nn * D;

    // ---- Part A: SpMM + bi-interaction ----
    hipMemsetAsync(side, 0, (size_t)Nn * D * sizeof(float), stream);
    ego2bf16_kernel<<<2048, 256, 0, stream>>>(ego, egob, (size_t)Nn * (D / 4));
    spmm_kernel<<<(nnz + 255) / 256, 256, 0, stream>>>(egob, vals, rows, cols, side, nnz);
    bi_gemm_mfma<<<dim3(2, (Nn + 127) / 128), 256, 0, stream>>>(
        ego, side, W1, b1, W2, b2, outAgg, Nn);

    // ---- Part B: transformer encoder ----
    const float* x = enc_in;
    for (int i = 0; i < NL; ++i) {
        const size_t wOff = (size_t)i * D * D;
        qkv_mfma<<<dim3(6, Menc / 128), 256, 0, stream>>>(
            x, wq + wOff, wk + wOff, wv + wOff,
            bq + (size_t)i * D, bk + (size_t)i * D, bv + (size_t)i * D,
            Qb, Kb, Vb, Menc, D);
        attn_kernel<<<Bb * NH * 2, 128, 0, stream>>>(Qb, Kb, Vb, Ob, NH);
        gemm_mfma<<<dim3(2, Menc / 128), 256, 0, stream>>>(
            Ob, wo + wOff, bo + (size_t)i * D, x, Tb, Menc, D, D, 0);
        ln_kernel<<<Menc / 4, 256, 0, stream>>>(
            Tb, ln1_g + (size_t)i * D, ln1_b + (size_t)i * D, XA, Menc);
        gemm_mfma<<<dim3(DI / 64, Menc / 128), 256, 0, stream>>>(
            XA, cw1 + (size_t)i * D * DI, cb1 + (size_t)i * DI, nullptr, Hb, Menc, DI, D, 1);
        gemm_mfma<<<dim3(2, Menc / 128), 256, 0, stream>>>(
            Hb, cw2 + (size_t)i * DI * D, cb2 + (size_t)i * D, XA, Tb, Menc, D, DI, 0);
        if (i == NL - 1) {
            ln_kernel<<<Menc / 4, 256, 0, stream>>>(
                Tb, ln2_g + (size_t)i * D, ln2_b + (size_t)i * D, outX, Menc);
        } else {
            ln_kernel<<<Menc / 4, 256, 0, stream>>>(
                Tb, ln2_g + (size_t)i * D, ln2_b + (size_t)i * D, XB, Menc);
            x = XB;
        }
    }
}

// Round 3
// 607.844 us; speedup vs baseline: 1.0651x; 1.0006x over previous
//
#include <hip/hip_runtime.h>

typedef __attribute__((ext_vector_type(8))) short bf16x8;
typedef __attribute__((ext_vector_type(4))) float f32x4;

__device__ __forceinline__ unsigned short f2b(float f) {
    union { float f; unsigned int i; } u; u.f = f;
    return (unsigned short)((u.i + 0x7FFFu + ((u.i >> 16) & 1u)) >> 16);
}
__device__ __forceinline__ unsigned int packbf2(float a, float b) {
    return (unsigned int)f2b(a) | ((unsigned int)f2b(b) << 16);
}

// ---------------------------------------------------------------------------
// ego -> bf16 copy (packed 2/uint). Streaming, grid-stride.
// ---------------------------------------------------------------------------
__global__ __launch_bounds__(256) void ego2bf16_kernel(
    const float* __restrict__ ego, unsigned int* __restrict__ egob, size_t n4)
{
    size_t i = (size_t)blockIdx.x * 256 + threadIdx.x;
    size_t stride = (size_t)gridDim.x * 256;
    for (; i < n4; i += stride) {
        float4 a = *(const float4*)(ego + i * 4);
        uint2 p;
        p.x = packbf2(a.x, a.y);
        p.y = packbf2(a.z, a.w);
        *(uint2*)(egob + i * 2) = p;
    }
}

// ---------------------------------------------------------------------------
// SpMM: side[r,:] += vals[e] * ego_bf16[cols[e],:]  (rows sorted).
// Block = 256 threads = 4 independent waves; each wave owns 64 edges; lane
// holds 2 columns packed in one dword (bf16x2).
// Per-edge metadata (row/col/val) is wave-uniform: lane i loads edge i's
// metadata once (coalesced); the fully-unrolled 64-edge loop broadcasts it
// with v_readlane into SGPRs. Row-transition test is a scalar branch; gather
// uses a uniform (SGPR) row base + constant lane*4 vaddr.
// Depth-40 register prefetch queue (40 VGPRs; total ~60 stays under the
// 64-VGPR / 8-waves-per-SIMD occupancy cliff) to cover ~800 cyc of gather
// latency -- the gather working set (25.6 MB) misses per-XCD L2 ~44% of the
// time and those misses cost L3 latency (~500 cyc).
// Tail waves clamp to the last edge with val=0 (contributes nothing), so the
// loop has no bounds checks at all.
// ---------------------------------------------------------------------------
#define PRE_DEPTH 40

__global__ __launch_bounds__(256) void spmm_kernel(
    const unsigned int* __restrict__ egob, const float* __restrict__ vals,
    const int* __restrict__ rows, const int* __restrict__ cols,
    float* __restrict__ side, int nnz)
{
    int tid = threadIdx.x;
    int wave = tid >> 6, lane = tid & 63;
    int e0 = blockIdx.x * 256 + wave * 64;
    if (e0 >= nnz) return;

    int idx = e0 + lane;
    int last = nnz - 1;
    bool ok = idx < nnz;
    int safe = ok ? idx : last;
    int my_row = rows[safe];
    int my_col = cols[safe];
    float my_val = ok ? vals[safe] : 0.f;

    unsigned int pre[PRE_DEPTH];
    #pragma unroll
    for (int j = 0; j < PRE_DEPTH; ++j) {
        unsigned int c = (unsigned int)__builtin_amdgcn_readlane(my_col, j);
        pre[j] = *(egob + ((size_t)c << 6) + lane);
    }

    float ax = 0.f, ay = 0.f;
    int cur = __builtin_amdgcn_readlane(my_row, 0);
    #pragma unroll
    for (int e = 0; e < 64; ++e) {
        int r = __builtin_amdgcn_readlane(my_row, e);
        float vv = __int_as_float(__builtin_amdgcn_readlane(__float_as_int(my_val), e));
        unsigned int u = pre[e % PRE_DEPTH];
        if (e < 64 - PRE_DEPTH) {
            unsigned int c = (unsigned int)__builtin_amdgcn_readlane(my_col, e + PRE_DEPTH);
            pre[e % PRE_DEPTH] = *(egob + ((size_t)c << 6) + lane);
        }
        if (r != cur) {
            atomicAdd(&side[(size_t)cur * 128 + lane * 2], ax);
            atomicAdd(&side[(size_t)cur * 128 + lane * 2 + 1], ay);
            ax = 0.f; ay = 0.f; cur = r;
        }
        ax = fmaf(vv, __uint_as_float(u << 16), ax);
        ay = fmaf(vv, __uint_as_float(u & 0xFFFF0000u), ay);
    }
    atomicAdd(&side[(size_t)cur * 128 + lane * 2], ax);
    atomicAdd(&side[(size_t)cur * 128 + lane * 2 + 1], ay);
}

// ---------------------------------------------------------------------------
// MFMA GEMM core: C[bm:bm+128, bn:bn+64] = act(A@W + bias [+R]).
// A f32 (M,K) row-major, W f32 (K,N) row-major, staged to LDS as bf16.
// 256 threads = 4 waves stacked in m (32 rows each), 16x16x32 bf16 MFMA.
// A-frag: A[m=lane&15][k=quad*8+j]; B-frag: B[k=quad*8+j][n=lane&15];
// C/D: col=lane&15, row=quad*4+reg.
// ---------------------------------------------------------------------------
#define LDAB 40   // bf16 row stride in LDS (pad: 80B rows -> 2-way conflicts only)

__device__ __forceinline__ void gemm_core(
    const float* __restrict__ A, const float* __restrict__ W,
    const float* __restrict__ bias, const float* __restrict__ R,
    float* __restrict__ C, int M, int N, int K, int act,
    int bm, int bn, unsigned short* As, unsigned short* Bs)
{
    int tid = threadIdx.x, wave = tid >> 6, lane = tid & 63;
    int lm = lane & 15, quad = lane >> 4;

    f32x4 acc[2][4];
    #pragma unroll
    for (int i = 0; i < 2; ++i)
        #pragma unroll
        for (int j = 0; j < 4; ++j) acc[i][j] = (f32x4)(0.f);

    for (int k0 = 0; k0 < K; k0 += 32) {
        // stage A tile: 128 rows x 32 k (bf16), 512 8-elem items
        #pragma unroll
        for (int it = 0; it < 2; ++it) {
            int i = tid + it * 256;
            int m = i >> 2, kc = (i & 3) * 8;
            int gm = bm + m;
            float4 a0, a1;
            if (gm < M) {
                const float* p = A + (size_t)gm * K + k0 + kc;
                a0 = *(const float4*)p; a1 = *(const float4*)(p + 4);
            } else { a0 = make_float4(0,0,0,0); a1 = a0; }
            uint4 pk;
            pk.x = packbf2(a0.x, a0.y); pk.y = packbf2(a0.z, a0.w);
            pk.z = packbf2(a1.x, a1.y); pk.w = packbf2(a1.z, a1.w);
            *(uint4*)&As[m * LDAB + kc] = pk;
        }
        // stage B tile transposed: Bs[n][k], 64 n x 32 k
        {
            int nn = tid & 63, kq = (tid >> 6) * 8;
            const float* p = W + (size_t)(k0 + kq) * N + bn + nn;
            float w[8];
            #pragma unroll
            for (int j = 0; j < 8; ++j) w[j] = p[(size_t)j * N];
            uint4 pk;
            pk.x = packbf2(w[0], w[1]); pk.y = packbf2(w[2], w[3]);
            pk.z = packbf2(w[4], w[5]); pk.w = packbf2(w[6], w[7]);
            *(uint4*)&Bs[nn * LDAB + kq] = pk;
        }
        __syncthreads();
        bf16x8 af[2], bfr[4];
        #pragma unroll
        for (int mi = 0; mi < 2; ++mi)
            af[mi] = *(bf16x8*)&As[(wave * 32 + mi * 16 + lm) * LDAB + quad * 8];
        #pragma unroll
        for (int ni = 0; ni < 4; ++ni)
            bfr[ni] = *(bf16x8*)&Bs[(ni * 16 + lm) * LDAB + quad * 8];
        #pragma unroll
        for (int mi = 0; mi < 2; ++mi)
            #pragma unroll
            for (int ni = 0; ni < 4; ++ni)
                acc[mi][ni] = __builtin_amdgcn_mfma_f32_16x16x32_bf16(
                    af[mi], bfr[ni], acc[mi][ni], 0, 0, 0);
        __syncthreads();
    }
    #pragma unroll
    for (int mi = 0; mi < 2; ++mi) {
        #pragma unroll
        for (int r = 0; r < 4; ++r) {
            int row = bm + wave * 32 + mi * 16 + quad * 4 + r;
            if (row < M) {
                #pragma unroll
                for (int ni = 0; ni < 4; ++ni) {
                    int col = bn + ni * 16 + lm;
                    float v = acc[mi][ni][r] + bias[col];
                    if (R) v += R[(size_t)row * N + col];
                    if (act) v = fmaxf(v, 0.f);
                    C[(size_t)row * N + col] = v;
                }
            }
        }
    }
}

__global__ __launch_bounds__(256) void gemm_mfma(
    const float* __restrict__ A, const float* __restrict__ W,
    const float* __restrict__ bias, const float* __restrict__ R,
    float* __restrict__ C, int M, int N, int K, int act)
{
    __shared__ unsigned short As[128 * LDAB];
    __shared__ unsigned short Bs[64 * LDAB];
    gemm_core(A, W, bias, R, C, M, N, K, act,
              blockIdx.y * 128, blockIdx.x * 64, As, Bs);
}

// fused Q/K/V projection: grid.x = 6 (3 outputs x 2 n-halves)
__global__ __launch_bounds__(256) void qkv_mfma(
    const float* __restrict__ A,
    const float* __restrict__ wq, const float* __restrict__ wk, const float* __restrict__ wv,
    const float* __restrict__ bq, const float* __restrict__ bk, const float* __restrict__ bv,
    float* __restrict__ Q, float* __restrict__ Ko, float* __restrict__ V, int M, int D)
{
    __shared__ unsigned short As[128 * LDAB];
    __shared__ unsigned short Bs[64 * LDAB];
    int sel = blockIdx.x >> 1;
    const float* W = (sel == 0) ? wq : (sel == 1) ? wk : wv;
    const float* b = (sel == 0) ? bq : (sel == 1) ? bk : bv;
    float* C = (sel == 0) ? Q : (sel == 1) ? Ko : V;
    gemm_core(A, W, b, nullptr, C, M, D, D, 0,
              blockIdx.y * 128, (blockIdx.x & 1) * 64, As, Bs);
}

// ---------------------------------------------------------------------------
// Bi-interaction fused MFMA GEMM:
//   agg = leaky((ego+side)@W1+b1) + leaky((ego*side)@W2+b2), K=N=128
// ---------------------------------------------------------------------------
__global__ __launch_bounds__(256) void bi_gemm_mfma(
    const float* __restrict__ ego, const float* __restrict__ side,
    const float* __restrict__ W1, const float* __restrict__ b1,
    const float* __restrict__ W2, const float* __restrict__ b2,
    float* __restrict__ out, int M)
{
    __shared__ unsigned short Us[128 * LDAB];
    __shared__ unsigned short Ms[128 * LDAB];
    __shared__ unsigned short W1s[64 * LDAB];
    __shared__ unsigned short W2s[64 * LDAB];

    int tid = threadIdx.x, wave = tid >> 6, lane = tid & 63;
    int lm = lane & 15, quad = lane >> 4;
    int bm = blockIdx.y * 128, bn = blockIdx.x * 64;

    f32x4 acc1[2][4], acc2[2][4];
    #pragma unroll
    for (int i = 0; i < 2; ++i)
        #pragma unroll
        for (int j = 0; j < 4; ++j) { acc1[i][j] = (f32x4)(0.f); acc2[i][j] = (f32x4)(0.f); }

    for (int k0 = 0; k0 < 128; k0 += 32) {
        #pragma unroll
        for (int it = 0; it < 2; ++it) {
            int i = tid + it * 256;
            int m = i >> 2, kc = (i & 3) * 8;
            int gm = bm + m;
            float e[8], s[8];
            if (gm < M) {
                const float* pe = ego + (size_t)gm * 128 + k0 + kc;
                const float* ps = side + (size_t)gm * 128 + k0 + kc;
                float4 e0 = *(const float4*)pe, e1 = *(const float4*)(pe + 4);
                float4 s0 = *(const float4*)ps, s1 = *(const float4*)(ps + 4);
                e[0]=e0.x; e[1]=e0.y; e[2]=e0.z; e[3]=e0.w;
                e[4]=e1.x; e[5]=e1.y; e[6]=e1.z; e[7]=e1.w;
                s[0]=s0.x; s[1]=s0.y; s[2]=s0.z; s[3]=s0.w;
                s[4]=s1.x; s[5]=s1.y; s[6]=s1.z; s[7]=s1.w;
            } else {
                #pragma unroll
                for (int j = 0; j < 8; ++j) { e[j] = 0.f; s[j] = 0.f; }
            }
            uint4 pu, pm;
            pu.x = packbf2(e[0]+s[0], e[1]+s[1]); pu.y = packbf2(e[2]+s[2], e[3]+s[3]);
            pu.z = packbf2(e[4]+s[4], e[5]+s[5]); pu.w = packbf2(e[6]+s[6], e[7]+s[7]);
            pm.x = packbf2(e[0]*s[0], e[1]*s[1]); pm.y = packbf2(e[2]*s[2], e[3]*s[3]);
            pm.z = packbf2(e[4]*s[4], e[5]*s[5]); pm.w = packbf2(e[6]*s[6], e[7]*s[7]);
            *(uint4*)&Us[m * LDAB + kc] = pu;
            *(uint4*)&Ms[m * LDAB + kc] = pm;
        }
        {
            int nn = tid & 63, kq = (tid >> 6) * 8;
            const float* p1 = W1 + (size_t)(k0 + kq) * 128 + bn + nn;
            const float* p2 = W2 + (size_t)(k0 + kq) * 128 + bn + nn;
            float wa[8], wb[8];
            #pragma unroll
            for (int j = 0; j < 8; ++j) { wa[j] = p1[(size_t)j * 128]; wb[j] = p2[(size_t)j * 128]; }
            uint4 pk1, pk2;
            pk1.x = packbf2(wa[0],wa[1]); pk1.y = packbf2(wa[2],wa[3]);
            pk1.z = packbf2(wa[4],wa[5]); pk1.w = packbf2(wa[6],wa[7]);
            pk2.x = packbf2(wb[0],wb[1]); pk2.y = packbf2(wb[2],wb[3]);
            pk2.z = packbf2(wb[4],wb[5]); pk2.w = packbf2(wb[6],wb[7]);
            *(uint4*)&W1s[nn * LDAB + kq] = pk1;
            *(uint4*)&W2s[nn * LDAB + kq] = pk2;
        }
        __syncthreads();
        bf16x8 au[2], am[2], bf1[4], bf2[4];
        #pragma unroll
        for (int mi = 0; mi < 2; ++mi) {
            au[mi] = *(bf16x8*)&Us[(wave * 32 + mi * 16 + lm) * LDAB + quad * 8];
            am[mi] = *(bf16x8*)&Ms[(wave * 32 + mi * 16 + lm) * LDAB + quad * 8];
        }
        #pragma unroll
        for (int ni = 0; ni < 4; ++ni) {
            bf1[ni] = *(bf16x8*)&W1s[(ni * 16 + lm) * LDAB + quad * 8];
            bf2[ni] = *(bf16x8*)&W2s[(ni * 16 + lm) * LDAB + quad * 8];
        }
        #pragma unroll
        for (int mi = 0; mi < 2; ++mi)
            #pragma unroll
            for (int ni = 0; ni < 4; ++ni) {
                acc1[mi][ni] = __builtin_amdgcn_mfma_f32_16x16x32_bf16(
                    au[mi], bf1[ni], acc1[mi][ni], 0, 0, 0);
                acc2[mi][ni] = __builtin_amdgcn_mfma_f32_16x16x32_bf16(
                    am[mi], bf2[ni], acc2[mi][ni], 0, 0, 0);
            }
        __syncthreads();
    }
    #pragma unroll
    for (int mi = 0; mi < 2; ++mi) {
        #pragma unroll
        for (int r = 0; r < 4; ++r) {
            int row = bm + wave * 32 + mi * 16 + quad * 4 + r;
            if (row < M) {
                #pragma unroll
                for (int ni = 0; ni < 4; ++ni) {
                    int col = bn + ni * 16 + lm;
                    float v1 = acc1[mi][ni][r] + b1[col];
                    v1 = v1 > 0.f ? v1 : 0.01f * v1;
                    float v2 = acc2[mi][ni][r] + b2[col];
                    v2 = v2 > 0.f ? v2 : 0.01f * v2;
                    out[(size_t)row * 128 + col] = v1 + v2;
                }
            }
        }
    }
}

// ---------------------------------------------------------------------------
// Attention: block = (b, h, half of queries), 128 threads, single-pass
// online softmax. L == 256, DK == 16.
// ---------------------------------------------------------------------------
__global__ __launch_bounds__(128) void attn_kernel(
    const float* __restrict__ q, const float* __restrict__ k,
    const float* __restrict__ v, float* __restrict__ o, int NH)
{
    const int L = 256, DK = 16;
    __shared__ float Ks[L * DK];
    __shared__ float Vs[L * DK];
    int bh = blockIdx.x >> 1;
    int half = blockIdx.x & 1;
    int b = bh / NH, h = bh % NH;
    int tid = threadIdx.x;

    for (int i = tid; i < L * 4; i += 128) {
        int l = i >> 2, d4 = (i & 3) * 4;
        size_t g = ((size_t)(b * L + l) * NH + h) * DK + d4;
        *(float4*)&Ks[l * 16 + d4] = *(const float4*)(k + g);
        *(float4*)&Vs[l * 16 + d4] = *(const float4*)(v + g);
    }
    __syncthreads();

    int l = half * 128 + tid;
    size_t qbase = ((size_t)(b * L + l) * NH + h) * DK;
    float qr[16];
    #pragma unroll
    for (int d4 = 0; d4 < 4; ++d4) {
        float4 t = *(const float4*)(q + qbase + d4 * 4);
        qr[d4*4+0] = t.x * 0.25f; qr[d4*4+1] = t.y * 0.25f;
        qr[d4*4+2] = t.z * 0.25f; qr[d4*4+3] = t.w * 0.25f;
    }
    float acc[16];
    #pragma unroll
    for (int d = 0; d < 16; ++d) acc[d] = 0.f;
    float mmax = -1e30f, ssum = 0.f;
    for (int kk = 0; kk < L; ++kk) {
        float dot = 0.f;
        #pragma unroll
        for (int d4 = 0; d4 < 4; ++d4) {
            float4 kv = *(const float4*)&Ks[kk * 16 + d4 * 4];
            dot = fmaf(qr[d4*4+0], kv.x, dot);
            dot = fmaf(qr[d4*4+1], kv.y, dot);
            dot = fmaf(qr[d4*4+2], kv.z, dot);
            dot = fmaf(qr[d4*4+3], kv.w, dot);
        }
        if (dot > mmax) {
            float alpha = __expf(mmax - dot);
            ssum *= alpha;
            #pragma unroll
            for (int d = 0; d < 16; ++d) acc[d] *= alpha;
            mmax = dot;
        }
        float p = __expf(dot - mmax);
        ssum += p;
        #pragma unroll
        for (int d4 = 0; d4 < 4; ++d4) {
            float4 vv = *(const float4*)&Vs[kk * 16 + d4 * 4];
            acc[d4*4+0] = fmaf(p, vv.x, acc[d4*4+0]);
            acc[d4*4+1] = fmaf(p, vv.y, acc[d4*4+1]);
            acc[d4*4+2] = fmaf(p, vv.z, acc[d4*4+2]);
            acc[d4*4+3] = fmaf(p, vv.w, acc[d4*4+3]);
        }
    }
    float inv = 1.f / ssum;
    #pragma unroll
    for (int d4 = 0; d4 < 4; ++d4) {
        float4 t;
        t.x = acc[d4*4+0] * inv; t.y = acc[d4*4+1] * inv;
        t.z = acc[d4*4+2] * inv; t.w = acc[d4*4+3] * inv;
        *(float4*)(o + qbase + d4 * 4) = t;
    }
}

// ---------------------------------------------------------------------------
// LayerNorm over rows of 128. One wave per row (2 elems/lane).
// ---------------------------------------------------------------------------
__global__ __launch_bounds__(256) void ln_kernel(
    const float* __restrict__ X, const float* __restrict__ g,
    const float* __restrict__ b, float* __restrict__ outF, int Mrows)
{
    int wave = threadIdx.x >> 6;
    int lane = threadIdx.x & 63;
    int r = blockIdx.x * 4 + wave;
    if (r >= Mrows) return;

    float2 x2 = *(const float2*)(X + (size_t)r * 128 + lane * 2);
    float s = x2.x + x2.y;
    float ss = x2.x * x2.x + x2.y * x2.y;
    #pragma unroll
    for (int off = 32; off > 0; off >>= 1) {
        s  += __shfl_xor(s, off, 64);
        ss += __shfl_xor(ss, off, 64);
    }
    float mean = s * (1.f / 128.f);
    float var = ss * (1.f / 128.f) - mean * mean;
    float rstd = rsqrtf(var + 1e-5f);
    float y0 = (x2.x - mean) * rstd * g[lane * 2 + 0] + b[lane * 2 + 0];
    float y1 = (x2.y - mean) * rstd * g[lane * 2 + 1] + b[lane * 2 + 1];
    *(float2*)(outF + (size_t)r * 128 + lane * 2) = make_float2(y0, y1);
}

extern "C" void kernel_launch(void* const* d_in, const int* in_sizes, int n_in,
                              void* d_out, int out_size, void* d_ws, size_t ws_size,
                              hipStream_t stream) {
    const float* ego    = (const float*)d_in[0];
    const float* vals   = (const float*)d_in[1];
    const float* W1     = (const float*)d_in[2];
    const float* b1     = (const float*)d_in[3];
    const float* W2     = (const float*)d_in[4];
    const float* b2     = (const float*)d_in[5];
    const float* enc_in = (const float*)d_in[6];
    const float* wq  = (const float*)d_in[7];
    const float* bq  = (const float*)d_in[8];
    const float* wk  = (const float*)d_in[9];
    const float* bk  = (const float*)d_in[10];
    const float* wv  = (const float*)d_in[11];
    const float* bv  = (const float*)d_in[12];
    const float* wo  = (const float*)d_in[13];
    const float* bo  = (const float*)d_in[14];
    const float* ln1_g = (const float*)d_in[15];
    const float* ln1_b = (const float*)d_in[16];
    const float* cw1 = (const float*)d_in[17];
    const float* cb1 = (const float*)d_in[18];
    const float* cw2 = (const float*)d_in[19];
    const float* cb2 = (const float*)d_in[20];
    const float* ln2_g = (const float*)d_in[21];
    const float* ln2_b = (const float*)d_in[22];
    const int* rows = (const int*)d_in[23];
    const int* cols = (const int*)d_in[24];

    const int D = 128, DI = 512, NH = 8, L = 256;
    const int Nn   = in_sizes[0] / D;        // 100000
    const int nnz  = in_sizes[1];            // 2000000
    const int NL   = in_sizes[7] / (D * D);  // 2
    const int Menc = in_sizes[6] / D;        // 8192 (= B*L)
    const int Bb   = Menc / L;               // 32

    float* ws = (float*)d_ws;
    size_t off = 0;
    float* side = ws + off; off += (size_t)Nn * D;
    float* Qb = ws + off; off += (size_t)Menc * D;
    float* Kb = ws + off; off += (size_t)Menc * D;
    float* Vb = ws + off; off += (size_t)Menc * D;
    float* Ob = ws + off; off += (size_t)Menc * D;
    float* Tb = ws + off; off += (size_t)Menc * D;
    float* XA = ws + off; off += (size_t)Menc * D;
    float* XB = ws + off; off += (size_t)Menc * D;
    float* Hb = ws + off; off += (size_t)Menc * DI;
    unsigned int* egob = (unsigned int*)(ws + off); off += (size_t)Nn * (D / 2); // bf16 copy of ego

    float* outAgg = (float*)d_out;
    float* outX   = (float*)d_out + (size_t)Nn * D;

    // ---- Part A: SpMM + bi-interaction ----
    hipMemsetAsync(side, 0, (size_t)Nn * D * sizeof(float), stream);
    ego2bf16_kernel<<<2048, 256, 0, stream>>>(ego, egob, (size_t)Nn * (D / 4));
    spmm_kernel<<<(nnz + 255) / 256, 256, 0, stream>>>(egob, vals, rows, cols, side, nnz);
    bi_gemm_mfma<<<dim3(2, (Nn + 127) / 128), 256, 0, stream>>>(
        ego, side, W1, b1, W2, b2, outAgg, Nn);

    // ---- Part B: transformer encoder ----
    const float* x = enc_in;
    for (int i = 0; i < NL; ++i) {
        const size_t wOff = (size_t)i * D * D;
        qkv_mfma<<<dim3(6, Menc / 128), 256, 0, stream>>>(
            x, wq + wOff, wk + wOff, wv + wOff,
            bq + (size_t)i * D, bk + (size_t)i * D, bv + (size_t)i * D,
            Qb, Kb, Vb, Menc, D);
        attn_kernel<<<Bb * NH * 2, 128, 0, stream>>>(Qb, Kb, Vb, Ob, NH);
        gemm_mfma<<<dim3(2, Menc / 128), 256, 0, stream>>>(
            Ob, wo + wOff, bo + (size_t)i * D, x, Tb, Menc, D, D, 0);
        ln_kernel<<<Menc / 4, 256, 0, stream>>>(
            Tb, ln1_g + (size_t)i * D, ln1_b + (size_t)i * D, XA, Menc);
        gemm_mfma<<<dim3(DI / 64, Menc / 128), 256, 0, stream>>>(
            XA, cw1 + (size_t)i * D * DI, cb1 + (size_t)i * DI, nullptr, Hb, Menc, DI, D, 1);
        gemm_mfma<<<dim3(2, Menc / 128), 256, 0, stream>>>(
            Hb, cw2 + (size_t)i * DI * D, cb2 + (size_t)i * D, XA, Tb, Menc, D, DI, 0);
        if (i == NL - 1) {
            ln_kernel<<<Menc / 4, 256, 0, stream>>>(
                Tb, ln2_g + (size_t)i * D, ln2_b + (size_t)i * D, outX, Menc);
        } else {
            ln_kernel<<<Menc / 4, 256, 0, stream>>>(
                Tb, ln2_g + (size_t)i * D, ln2_b + (size_t)i * D, XB, Menc);
            x = XB;
        }
    }
}

// Round 4
// 570.163 us; speedup vs baseline: 1.1355x; 1.0661x over previous
//
#include <hip/hip_runtime.h>

typedef __attribute__((ext_vector_type(8))) short bf16x8;
typedef __attribute__((ext_vector_type(4))) float f32x4;

__device__ __forceinline__ unsigned short f2b(float f) {
    union { float f; unsigned int i; } u; u.f = f;
    return (unsigned short)((u.i + 0x7FFFu + ((u.i >> 16) & 1u)) >> 16);
}
__device__ __forceinline__ unsigned int packbf2(float a, float b) {
    return (unsigned int)f2b(a) | ((unsigned int)f2b(b) << 16);
}

// ---------------------------------------------------------------------------
// ego -> bf16 copy (packed 2/uint). Streaming, grid-stride.
// ---------------------------------------------------------------------------
__global__ __launch_bounds__(256) void ego2bf16_kernel(
    const float* __restrict__ ego, unsigned int* __restrict__ egob, size_t n4)
{
    size_t i = (size_t)blockIdx.x * 256 + threadIdx.x;
    size_t stride = (size_t)gridDim.x * 256;
    for (; i < n4; i += stride) {
        float4 a = *(const float4*)(ego + i * 4);
        uint2 p;
        p.x = packbf2(a.x, a.y);
        p.y = packbf2(a.z, a.w);
        *(uint2*)(egob + i * 2) = p;
    }
}

// ---------------------------------------------------------------------------
// SpMM: side[r,:] += vals[e] * ego_bf16[cols[e],:]  (rows sorted).
// 4 independent waves/block; wave owns 64 edges; lane holds 2 cols (bf16x2).
// Metadata broadcast via v_readlane (scalar pipe); row-transition is a
// scalar branch; gather = uniform SGPR row base + constant lane*4 vaddr.
// Depth-16 register prefetch queue (R3 showed deeper queues are defeated by
// the register allocator and per-wave MLP is not the limiter anyway).
// ---------------------------------------------------------------------------
__global__ __launch_bounds__(256) void spmm_kernel(
    const unsigned int* __restrict__ egob, const float* __restrict__ vals,
    const int* __restrict__ rows, const int* __restrict__ cols,
    float* __restrict__ side, int nnz)
{
    int tid = threadIdx.x;
    int wave = tid >> 6, lane = tid & 63;
    int e0 = blockIdx.x * 256 + wave * 64;
    if (e0 >= nnz) return;

    int idx = e0 + lane;
    int last = nnz - 1;
    bool ok = idx < nnz;
    int safe = ok ? idx : last;
    int my_row = rows[safe];
    int my_col = cols[safe];
    float my_val = ok ? vals[safe] : 0.f;

    unsigned int pre[16];
    #pragma unroll
    for (int j = 0; j < 16; ++j) {
        unsigned int c = (unsigned int)__builtin_amdgcn_readlane(my_col, j);
        pre[j] = *(egob + ((size_t)c << 6) + lane);
    }

    float ax = 0.f, ay = 0.f;
    int cur = __builtin_amdgcn_readlane(my_row, 0);
    #pragma unroll
    for (int e = 0; e < 64; ++e) {
        int r = __builtin_amdgcn_readlane(my_row, e);
        float vv = __int_as_float(__builtin_amdgcn_readlane(__float_as_int(my_val), e));
        unsigned int u = pre[e & 15];
        if (e < 48) {
            unsigned int c = (unsigned int)__builtin_amdgcn_readlane(my_col, e + 16);
            pre[e & 15] = *(egob + ((size_t)c << 6) + lane);
        }
        if (r != cur) {
            atomicAdd(&side[(size_t)cur * 128 + lane * 2], ax);
            atomicAdd(&side[(size_t)cur * 128 + lane * 2 + 1], ay);
            ax = 0.f; ay = 0.f; cur = r;
        }
        ax = fmaf(vv, __uint_as_float(u << 16), ax);
        ay = fmaf(vv, __uint_as_float(u & 0xFFFF0000u), ay);
    }
    atomicAdd(&side[(size_t)cur * 128 + lane * 2], ax);
    atomicAdd(&side[(size_t)cur * 128 + lane * 2 + 1], ay);
}

#define LDAB 40   // bf16 row stride in LDS (80B rows -> 2-way conflicts only)

// ---------------------------------------------------------------------------
// gemm2 core: BM=64 x BN=128 tile, 256 threads = 4 waves as 2(m) x 2(n).
// C[bm:bm+64, bn:bn+128] = act(A@W + bias [+R]) with optional fused
// row-LayerNorm (g,bta non-null; requires N==128, bn==0, grid.x==1).
// A f32 (M,K) row-major, W f32 (K,N) row-major, staged to LDS as bf16.
// A-frag: A[m=lane&15][k=quad*8+j]; B-frag: B[k=quad*8+j][n=lane&15];
// C/D: col=lane&15, row=quad*4+reg.
// LN: per row, 128 outputs live in one wave's 16-lane quad group (4 ni x
// 16 lm) x 2 n-waves -> shfl_xor butterfly over lm + tiny LDS cross-wave
// combine. Math order identical to the old ln_kernel.
// ---------------------------------------------------------------------------
__device__ __forceinline__ void gemm2_core(
    const float* __restrict__ A, const float* __restrict__ W,
    const float* __restrict__ bias, const float* __restrict__ R,
    const float* __restrict__ g, const float* __restrict__ bta,
    float* __restrict__ C, int M, int N, int K, int act,
    int bm, int bn, unsigned short* As, unsigned short* Bs,
    float* redS, float* redSS)
{
    int tid = threadIdx.x, wave = tid >> 6, lane = tid & 63;
    int lm = lane & 15, quad = lane >> 4;
    int wm = wave >> 1, wn = wave & 1;

    f32x4 acc[2][4];
    #pragma unroll
    for (int i = 0; i < 2; ++i)
        #pragma unroll
        for (int j = 0; j < 4; ++j) acc[i][j] = (f32x4)(0.f);

    for (int k0 = 0; k0 < K; k0 += 32) {
        // stage A tile: 64 rows x 32 k (bf16); item tid: m=tid>>2, kc=(tid&3)*8
        {
            int m = tid >> 2, kc = (tid & 3) * 8;
            const float* p = A + (size_t)(bm + m) * K + k0 + kc;
            float4 a0 = *(const float4*)p, a1 = *(const float4*)(p + 4);
            uint4 pk;
            pk.x = packbf2(a0.x, a0.y); pk.y = packbf2(a0.z, a0.w);
            pk.z = packbf2(a1.x, a1.y); pk.w = packbf2(a1.z, a1.w);
            *(uint4*)&As[m * LDAB + kc] = pk;
        }
        // stage B tile transposed: Bs[n][k], 128 n x 32 k; thread covers 16 k
        {
            int nn = tid & 127, kh = (tid >> 7) * 16;
            const float* p = W + (size_t)(k0 + kh) * N + bn + nn;
            float w[16];
            #pragma unroll
            for (int j = 0; j < 16; ++j) w[j] = p[(size_t)j * N];
            uint4 pk;
            pk.x = packbf2(w[0], w[1]);  pk.y = packbf2(w[2], w[3]);
            pk.z = packbf2(w[4], w[5]);  pk.w = packbf2(w[6], w[7]);
            *(uint4*)&Bs[nn * LDAB + kh] = pk;
            pk.x = packbf2(w[8], w[9]);  pk.y = packbf2(w[10], w[11]);
            pk.z = packbf2(w[12], w[13]); pk.w = packbf2(w[14], w[15]);
            *(uint4*)&Bs[nn * LDAB + kh + 8] = pk;
        }
        __syncthreads();
        bf16x8 af[2], bfr[4];
        #pragma unroll
        for (int mi = 0; mi < 2; ++mi)
            af[mi] = *(bf16x8*)&As[(wm * 32 + mi * 16 + lm) * LDAB + quad * 8];
        #pragma unroll
        for (int ni = 0; ni < 4; ++ni)
            bfr[ni] = *(bf16x8*)&Bs[(wn * 64 + ni * 16 + lm) * LDAB + quad * 8];
        #pragma unroll
        for (int mi = 0; mi < 2; ++mi)
            #pragma unroll
            for (int ni = 0; ni < 4; ++ni)
                acc[mi][ni] = __builtin_amdgcn_mfma_f32_16x16x32_bf16(
                    af[mi], bfr[ni], acc[mi][ni], 0, 0, 0);
        __syncthreads();
    }

    // epilogue: bias (+R) (+relu) in place
    #pragma unroll
    for (int mi = 0; mi < 2; ++mi) {
        #pragma unroll
        for (int r = 0; r < 4; ++r) {
            int row = bm + wm * 32 + mi * 16 + quad * 4 + r;
            #pragma unroll
            for (int ni = 0; ni < 4; ++ni) {
                int col = bn + wn * 64 + ni * 16 + lm;
                float v = acc[mi][ni][r] + bias[col];
                if (R) v += R[(size_t)row * N + col];
                if (act) v = fmaxf(v, 0.f);
                acc[mi][ni][r] = v;
            }
        }
    }

    if (g) {
        // fused LayerNorm over rows of 128 (bn==0, N==128)
        #pragma unroll
        for (int mi = 0; mi < 2; ++mi) {
            #pragma unroll
            for (int r = 0; r < 4; ++r) {
                float s = 0.f, ss = 0.f;
                #pragma unroll
                for (int ni = 0; ni < 4; ++ni) {
                    float v = acc[mi][ni][r];
                    s += v; ss = fmaf(v, v, ss);
                }
                #pragma unroll
                for (int off = 1; off < 16; off <<= 1) {
                    s  += __shfl_xor(s, off, 64);
                    ss += __shfl_xor(ss, off, 64);
                }
                if (lm == 0) {
                    int lr = wm * 32 + mi * 16 + quad * 4 + r;
                    redS[wn * 64 + lr] = s;
                    redSS[wn * 64 + lr] = ss;
                }
            }
        }
        __syncthreads();
        #pragma unroll
        for (int mi = 0; mi < 2; ++mi) {
            #pragma unroll
            for (int r = 0; r < 4; ++r) {
                int lr = wm * 32 + mi * 16 + quad * 4 + r;
                int row = bm + lr;
                float s = redS[lr] + redS[64 + lr];
                float ss = redSS[lr] + redSS[64 + lr];
                float mean = s * (1.f / 128.f);
                float var = ss * (1.f / 128.f) - mean * mean;
                float rstd = rsqrtf(var + 1e-5f);
                #pragma unroll
                for (int ni = 0; ni < 4; ++ni) {
                    int col = wn * 64 + ni * 16 + lm;
                    float y = (acc[mi][ni][r] - mean) * rstd * g[col] + bta[col];
                    C[(size_t)row * 128 + col] = y;
                }
            }
        }
    } else {
        #pragma unroll
        for (int mi = 0; mi < 2; ++mi) {
            #pragma unroll
            for (int r = 0; r < 4; ++r) {
                int row = bm + wm * 32 + mi * 16 + quad * 4 + r;
                #pragma unroll
                for (int ni = 0; ni < 4; ++ni) {
                    int col = bn + wn * 64 + ni * 16 + lm;
                    C[(size_t)row * N + col] = acc[mi][ni][r];
                }
            }
        }
    }
}

__global__ __launch_bounds__(256) void gemm2_mfma(
    const float* __restrict__ A, const float* __restrict__ W,
    const float* __restrict__ bias, const float* __restrict__ R,
    const float* __restrict__ g, const float* __restrict__ bta,
    float* __restrict__ C, int M, int N, int K, int act)
{
    __shared__ unsigned short As[64 * LDAB];
    __shared__ unsigned short Bs[128 * LDAB];
    __shared__ float redS[128], redSS[128];
    gemm2_core(A, W, bias, R, g, bta, C, M, N, K, act,
               blockIdx.y * 64, blockIdx.x * 128, As, Bs, redS, redSS);
}

// fused Q/K/V projection: grid.x = 3 (Q, K, V), N = K = 128
__global__ __launch_bounds__(256) void qkv2_mfma(
    const float* __restrict__ A,
    const float* __restrict__ wq, const float* __restrict__ wk, const float* __restrict__ wv,
    const float* __restrict__ bq, const float* __restrict__ bk, const float* __restrict__ bv,
    float* __restrict__ Q, float* __restrict__ Ko, float* __restrict__ V, int M)
{
    __shared__ unsigned short As[64 * LDAB];
    __shared__ unsigned short Bs[128 * LDAB];
    __shared__ float redS[128], redSS[128];
    int sel = blockIdx.x;
    const float* W = (sel == 0) ? wq : (sel == 1) ? wk : wv;
    const float* b = (sel == 0) ? bq : (sel == 1) ? bk : bv;
    float* C = (sel == 0) ? Q : (sel == 1) ? Ko : V;
    gemm2_core(A, W, b, nullptr, nullptr, nullptr, C, M, 128, 128, 0,
               blockIdx.y * 64, 0, As, Bs, redS, redSS);
}

// ---------------------------------------------------------------------------
// Bi-interaction fused MFMA GEMM:
//   agg = leaky((ego+side)@W1+b1) + leaky((ego*side)@W2+b2), K=N=128
// ---------------------------------------------------------------------------
__global__ __launch_bounds__(256) void bi_gemm_mfma(
    const float* __restrict__ ego, const float* __restrict__ side,
    const float* __restrict__ W1, const float* __restrict__ b1,
    const float* __restrict__ W2, const float* __restrict__ b2,
    float* __restrict__ out, int M)
{
    __shared__ unsigned short Us[128 * LDAB];
    __shared__ unsigned short Ms[128 * LDAB];
    __shared__ unsigned short W1s[64 * LDAB];
    __shared__ unsigned short W2s[64 * LDAB];

    int tid = threadIdx.x, wave = tid >> 6, lane = tid & 63;
    int lm = lane & 15, quad = lane >> 4;
    int bm = blockIdx.y * 128, bn = blockIdx.x * 64;

    f32x4 acc1[2][4], acc2[2][4];
    #pragma unroll
    for (int i = 0; i < 2; ++i)
        #pragma unroll
        for (int j = 0; j < 4; ++j) { acc1[i][j] = (f32x4)(0.f); acc2[i][j] = (f32x4)(0.f); }

    for (int k0 = 0; k0 < 128; k0 += 32) {
        #pragma unroll
        for (int it = 0; it < 2; ++it) {
            int i = tid + it * 256;
            int m = i >> 2, kc = (i & 3) * 8;
            int gm = bm + m;
            float e[8], s[8];
            if (gm < M) {
                const float* pe = ego + (size_t)gm * 128 + k0 + kc;
                const float* ps = side + (size_t)gm * 128 + k0 + kc;
                float4 e0 = *(const float4*)pe, e1 = *(const float4*)(pe + 4);
                float4 s0 = *(const float4*)ps, s1 = *(const float4*)(ps + 4);
                e[0]=e0.x; e[1]=e0.y; e[2]=e0.z; e[3]=e0.w;
                e[4]=e1.x; e[5]=e1.y; e[6]=e1.z; e[7]=e1.w;
                s[0]=s0.x; s[1]=s0.y; s[2]=s0.z; s[3]=s0.w;
                s[4]=s1.x; s[5]=s1.y; s[6]=s1.z; s[7]=s1.w;
            } else {
                #pragma unroll
                for (int j = 0; j < 8; ++j) { e[j] = 0.f; s[j] = 0.f; }
            }
            uint4 pu, pm;
            pu.x = packbf2(e[0]+s[0], e[1]+s[1]); pu.y = packbf2(e[2]+s[2], e[3]+s[3]);
            pu.z = packbf2(e[4]+s[4], e[5]+s[5]); pu.w = packbf2(e[6]+s[6], e[7]+s[7]);
            pm.x = packbf2(e[0]*s[0], e[1]*s[1]); pm.y = packbf2(e[2]*s[2], e[3]*s[3]);
            pm.z = packbf2(e[4]*s[4], e[5]*s[5]); pm.w = packbf2(e[6]*s[6], e[7]*s[7]);
            *(uint4*)&Us[m * LDAB + kc] = pu;
            *(uint4*)&Ms[m * LDAB + kc] = pm;
        }
        {
            int nn = tid & 63, kq = (tid >> 6) * 8;
            const float* p1 = W1 + (size_t)(k0 + kq) * 128 + bn + nn;
            const float* p2 = W2 + (size_t)(k0 + kq) * 128 + bn + nn;
            float wa[8], wb[8];
            #pragma unroll
            for (int j = 0; j < 8; ++j) { wa[j] = p1[(size_t)j * 128]; wb[j] = p2[(size_t)j * 128]; }
            uint4 pk1, pk2;
            pk1.x = packbf2(wa[0],wa[1]); pk1.y = packbf2(wa[2],wa[3]);
            pk1.z = packbf2(wa[4],wa[5]); pk1.w = packbf2(wa[6],wa[7]);
            pk2.x = packbf2(wb[0],wb[1]); pk2.y = packbf2(wb[2],wb[3]);
            pk2.z = packbf2(wb[4],wb[5]); pk2.w = packbf2(wb[6],wb[7]);
            *(uint4*)&W1s[nn * LDAB + kq] = pk1;
            *(uint4*)&W2s[nn * LDAB + kq] = pk2;
        }
        __syncthreads();
        bf16x8 au[2], am[2], bf1[4], bf2[4];
        #pragma unroll
        for (int mi = 0; mi < 2; ++mi) {
            au[mi] = *(bf16x8*)&Us[(wave * 32 + mi * 16 + lm) * LDAB + quad * 8];
            am[mi] = *(bf16x8*)&Ms[(wave * 32 + mi * 16 + lm) * LDAB + quad * 8];
        }
        #pragma unroll
        for (int ni = 0; ni < 4; ++ni) {
            bf1[ni] = *(bf16x8*)&W1s[(ni * 16 + lm) * LDAB + quad * 8];
            bf2[ni] = *(bf16x8*)&W2s[(ni * 16 + lm) * LDAB + quad * 8];
        }
        #pragma unroll
        for (int mi = 0; mi < 2; ++mi)
            #pragma unroll
            for (int ni = 0; ni < 4; ++ni) {
                acc1[mi][ni] = __builtin_amdgcn_mfma_f32_16x16x32_bf16(
                    au[mi], bf1[ni], acc1[mi][ni], 0, 0, 0);
                acc2[mi][ni] = __builtin_amdgcn_mfma_f32_16x16x32_bf16(
                    am[mi], bf2[ni], acc2[mi][ni], 0, 0, 0);
            }
        __syncthreads();
    }
    #pragma unroll
    for (int mi = 0; mi < 2; ++mi) {
        #pragma unroll
        for (int r = 0; r < 4; ++r) {
            int row = bm + wave * 32 + mi * 16 + quad * 4 + r;
            if (row < M) {
                #pragma unroll
                for (int ni = 0; ni < 4; ++ni) {
                    int col = bn + ni * 16 + lm;
                    float v1 = acc1[mi][ni][r] + b1[col];
                    v1 = v1 > 0.f ? v1 : 0.01f * v1;
                    float v2 = acc2[mi][ni][r] + b2[col];
                    v2 = v2 > 0.f ? v2 : 0.01f * v2;
                    out[(size_t)row * 128 + col] = v1 + v2;
                }
            }
        }
    }
}

// ---------------------------------------------------------------------------
// Attention: block = (b, h, half of queries), 128 threads, single-pass
// online softmax. L == 256, DK == 16. K/V staged in 2 chunks of 128 rows
// (16 KB LDS instead of 32 KB -> 10 blocks/CU instead of 5; online softmax
// spans chunks with identical f32 numerics).
// ---------------------------------------------------------------------------
__global__ __launch_bounds__(128) void attn_kernel(
    const float* __restrict__ q, const float* __restrict__ k,
    const float* __restrict__ v, float* __restrict__ o, int NH)
{
    const int L = 256, DK = 16;
    __shared__ float Ks[128 * DK];
    __shared__ float Vs[128 * DK];
    int bh = blockIdx.x >> 1;
    int half = blockIdx.x & 1;
    int b = bh / NH, h = bh % NH;
    int tid = threadIdx.x;

    int l = half * 128 + tid;
    size_t qbase = ((size_t)(b * L + l) * NH + h) * DK;
    float qr[16];
    #pragma unroll
    for (int d4 = 0; d4 < 4; ++d4) {
        float4 t = *(const float4*)(q + qbase + d4 * 4);
        qr[d4*4+0] = t.x * 0.25f; qr[d4*4+1] = t.y * 0.25f;
        qr[d4*4+2] = t.z * 0.25f; qr[d4*4+3] = t.w * 0.25f;
    }
    float acc[16];
    #pragma unroll
    for (int d = 0; d < 16; ++d) acc[d] = 0.f;
    float mmax = -1e30f, ssum = 0.f;

    for (int c0 = 0; c0 < L; c0 += 128) {
        __syncthreads();
        for (int i = tid; i < 128 * 4; i += 128) {
            int ll = i >> 2, d4 = (i & 3) * 4;
            size_t gg = ((size_t)(b * L + c0 + ll) * NH + h) * DK + d4;
            *(float4*)&Ks[ll * 16 + d4] = *(const float4*)(k + gg);
            *(float4*)&Vs[ll * 16 + d4] = *(const float4*)(v + gg);
        }
        __syncthreads();

        for (int kk = 0; kk < 128; ++kk) {
            float dot = 0.f;
            #pragma unroll
            for (int d4 = 0; d4 < 4; ++d4) {
                float4 kv = *(const float4*)&Ks[kk * 16 + d4 * 4];
                dot = fmaf(qr[d4*4+0], kv.x, dot);
                dot = fmaf(qr[d4*4+1], kv.y, dot);
                dot = fmaf(qr[d4*4+2], kv.z, dot);
                dot = fmaf(qr[d4*4+3], kv.w, dot);
            }
            if (dot > mmax) {
                float alpha = __expf(mmax - dot);
                ssum *= alpha;
                #pragma unroll
                for (int d = 0; d < 16; ++d) acc[d] *= alpha;
                mmax = dot;
            }
            float p = __expf(dot - mmax);
            ssum += p;
            #pragma unroll
            for (int d4 = 0; d4 < 4; ++d4) {
                float4 vv = *(const float4*)&Vs[kk * 16 + d4 * 4];
                acc[d4*4+0] = fmaf(p, vv.x, acc[d4*4+0]);
                acc[d4*4+1] = fmaf(p, vv.y, acc[d4*4+1]);
                acc[d4*4+2] = fmaf(p, vv.z, acc[d4*4+2]);
                acc[d4*4+3] = fmaf(p, vv.w, acc[d4*4+3]);
            }
        }
    }
    float inv = 1.f / ssum;
    #pragma unroll
    for (int d4 = 0; d4 < 4; ++d4) {
        float4 t;
        t.x = acc[d4*4+0] * inv; t.y = acc[d4*4+1] * inv;
        t.z = acc[d4*4+2] * inv; t.w = acc[d4*4+3] * inv;
        *(float4*)(o + qbase + d4 * 4) = t;
    }
}

extern "C" void kernel_launch(void* const* d_in, const int* in_sizes, int n_in,
                              void* d_out, int out_size, void* d_ws, size_t ws_size,
                              hipStream_t stream) {
    const float* ego    = (const float*)d_in[0];
    const float* vals   = (const float*)d_in[1];
    const float* W1     = (const float*)d_in[2];
    const float* b1     = (const float*)d_in[3];
    const float* W2     = (const float*)d_in[4];
    const float* b2     = (const float*)d_in[5];
    const float* enc_in = (const float*)d_in[6];
    const float* wq  = (const float*)d_in[7];
    const float* bq  = (const float*)d_in[8];
    const float* wk  = (const float*)d_in[9];
    const float* bk  = (const float*)d_in[10];
    const float* wv  = (const float*)d_in[11];
    const float* bv  = (const float*)d_in[12];
    const float* wo  = (const float*)d_in[13];
    const float* bo  = (const float*)d_in[14];
    const float* ln1_g = (const float*)d_in[15];
    const float* ln1_b = (const float*)d_in[16];
    const float* cw1 = (const float*)d_in[17];
    const float* cb1 = (const float*)d_in[18];
    const float* cw2 = (const float*)d_in[19];
    const float* cb2 = (const float*)d_in[20];
    const float* ln2_g = (const float*)d_in[21];
    const float* ln2_b = (const float*)d_in[22];
    const int* rows = (const int*)d_in[23];
    const int* cols = (const int*)d_in[24];

    const int D = 128, DI = 512, NH = 8, L = 256;
    const int Nn   = in_sizes[0] / D;        // 100000
    const int nnz  = in_sizes[1];            // 2000000
    const int NL   = in_sizes[7] / (D * D);  // 2
    const int Menc = in_sizes[6] / D;        // 8192 (= B*L)
    const int Bb   = Menc / L;               // 32

    float* ws = (float*)d_ws;
    size_t off = 0;
    float* side = ws + off; off += (size_t)Nn * D;
    float* Qb = ws + off; off += (size_t)Menc * D;
    float* Kb = ws + off; off += (size_t)Menc * D;
    float* Vb = ws + off; off += (size_t)Menc * D;
    float* Ob = ws + off; off += (size_t)Menc * D;
    float* XA = ws + off; off += (size_t)Menc * D;
    float* XB = ws + off; off += (size_t)Menc * D;
    float* Hb = ws + off; off += (size_t)Menc * DI;
    unsigned int* egob = (unsigned int*)(ws + off); off += (size_t)Nn * (D / 2); // bf16 ego

    float* outAgg = (float*)d_out;
    float* outX   = (float*)d_out + (size_t)Nn * D;

    // ---- Part A: SpMM + bi-interaction ----
    hipMemsetAsync(side, 0, (size_t)Nn * D * sizeof(float), stream);
    ego2bf16_kernel<<<2048, 256, 0, stream>>>(ego, egob, (size_t)Nn * (D / 4));
    spmm_kernel<<<(nnz + 255) / 256, 256, 0, stream>>>(egob, vals, rows, cols, side, nnz);
    bi_gemm_mfma<<<dim3(2, (Nn + 127) / 128), 256, 0, stream>>>(
        ego, side, W1, b1, W2, b2, outAgg, Nn);

    // ---- Part B: transformer encoder ----
    const float* x = enc_in;
    for (int i = 0; i < NL; ++i) {
        const size_t wOff = (size_t)i * D * D;
        qkv2_mfma<<<dim3(3, Menc / 64), 256, 0, stream>>>(
            x, wq + wOff, wk + wOff, wv + wOff,
            bq + (size_t)i * D, bk + (size_t)i * D, bv + (size_t)i * D,
            Qb, Kb, Vb, Menc);
        attn_kernel<<<Bb * NH * 2, 128, 0, stream>>>(Qb, Kb, Vb, Ob, NH);
        // MHA out-proj + residual + LN1 (fused)
        gemm2_mfma<<<dim3(1, Menc / 64), 256, 0, stream>>>(
            Ob, wo + wOff, bo + (size_t)i * D, x,
            ln1_g + (size_t)i * D, ln1_b + (size_t)i * D, XA, Menc, D, D, 0);
        // FFN up + relu
        gemm2_mfma<<<dim3(DI / 128, Menc / 64), 256, 0, stream>>>(
            XA, cw1 + (size_t)i * D * DI, cb1 + (size_t)i * DI, nullptr,
            nullptr, nullptr, Hb, Menc, DI, D, 1);
        // FFN down + residual + LN2 (fused)
        float* dst = (i == NL - 1) ? outX : XB;
        gemm2_mfma<<<dim3(1, Menc / 64), 256, 0, stream>>>(
            Hb, cw2 + (size_t)i * DI * D, cb2 + (size_t)i * D, XA,
            ln2_g + (size_t)i * D, ln2_b + (size_t)i * D, dst, Menc, D, DI, 0);
        x = XB;
    }
}

// Round 5
// 485.000 us; speedup vs baseline: 1.3349x; 1.1756x over previous
//
#include <hip/hip_runtime.h>

typedef __attribute__((ext_vector_type(8))) short bf16x8;
typedef __attribute__((ext_vector_type(4))) float f32x4;

__device__ __forceinline__ unsigned short f2b(float f) {
    union { float f; unsigned int i; } u; u.f = f;
    return (unsigned short)((u.i + 0x7FFFu + ((u.i >> 16) & 1u)) >> 16);
}
__device__ __forceinline__ unsigned int packbf2(float a, float b) {
    return (unsigned int)f2b(a) | ((unsigned int)f2b(b) << 16);
}

// ---------------------------------------------------------------------------
// ego -> bf16 copy (packed 2/uint). Streaming, grid-stride. Must complete
// before any fused spmm chunk runs (stream order guarantees it).
// ---------------------------------------------------------------------------
__global__ __launch_bounds__(256) void ego2bf16_kernel(
    const float* __restrict__ ego, unsigned int* __restrict__ egob, size_t n4)
{
    size_t i = (size_t)blockIdx.x * 256 + threadIdx.x;
    size_t stride = (size_t)gridDim.x * 256;
    for (; i < n4; i += stride) {
        float4 a = *(const float4*)(ego + i * 4);
        uint2 p;
        p.x = packbf2(a.x, a.y);
        p.y = packbf2(a.z, a.w);
        *(uint2*)(egob + i * 2) = p;
    }
}

// ---------------------------------------------------------------------------
// SpMM block (device fn): side[r,:] += vals[e] * ego_bf16[cols[e],:]
// (rows sorted). One call processes 256 edges (4 waves x 64). Metadata
// broadcast via v_readlane (scalar pipe); row transition = scalar branch;
// gather = uniform SGPR row base + constant lane*4 vaddr. Depth-16 register
// prefetch queue. Order-independent across blocks (atomics) -> chunks can be
// fused into any kernel launched after memset(side) + ego2bf16.
// ---------------------------------------------------------------------------
__device__ __forceinline__ void spmm_block(
    const unsigned int* __restrict__ egob, const float* __restrict__ vals,
    const int* __restrict__ rows, const int* __restrict__ cols,
    float* __restrict__ side, int nnz, int blk)
{
    int tid = threadIdx.x;
    int wave = tid >> 6, lane = tid & 63;
    int e0 = blk * 256 + wave * 64;
    if (e0 >= nnz) return;

    int idx = e0 + lane;
    int last = nnz - 1;
    bool ok = idx < nnz;
    int safe = ok ? idx : last;
    int my_row = rows[safe];
    int my_col = cols[safe];
    float my_val = ok ? vals[safe] : 0.f;

    unsigned int pre[16];
    #pragma unroll
    for (int j = 0; j < 16; ++j) {
        unsigned int c = (unsigned int)__builtin_amdgcn_readlane(my_col, j);
        pre[j] = *(egob + ((size_t)c << 6) + lane);
    }

    float ax = 0.f, ay = 0.f;
    int cur = __builtin_amdgcn_readlane(my_row, 0);
    #pragma unroll
    for (int e = 0; e < 64; ++e) {
        int r = __builtin_amdgcn_readlane(my_row, e);
        float vv = __int_as_float(__builtin_amdgcn_readlane(__float_as_int(my_val), e));
        unsigned int u = pre[e & 15];
        if (e < 48) {
            unsigned int c = (unsigned int)__builtin_amdgcn_readlane(my_col, e + 16);
            pre[e & 15] = *(egob + ((size_t)c << 6) + lane);
        }
        if (r != cur) {
            atomicAdd(&side[(size_t)cur * 128 + lane * 2], ax);
            atomicAdd(&side[(size_t)cur * 128 + lane * 2 + 1], ay);
            ax = 0.f; ay = 0.f; cur = r;
        }
        ax = fmaf(vv, __uint_as_float(u << 16), ax);
        ay = fmaf(vv, __uint_as_float(u & 0xFFFF0000u), ay);
    }
    atomicAdd(&side[(size_t)cur * 128 + lane * 2], ax);
    atomicAdd(&side[(size_t)cur * 128 + lane * 2 + 1], ay);
}

#define LDAB 40   // bf16 row stride in LDS (80B rows -> 2-way conflicts only)

// ---------------------------------------------------------------------------
// gemm2 core: BM=64 x BN=128 tile, 256 threads = 4 waves as 2(m) x 2(n).
// C[bm:bm+64, bn:bn+128] = act(A@W + bias [+R]) with optional fused
// row-LayerNorm (g,bta non-null; requires N==128, bn==0).
// ---------------------------------------------------------------------------
__device__ __forceinline__ void gemm2_core(
    const float* __restrict__ A, const float* __restrict__ W,
    const float* __restrict__ bias, const float* __restrict__ R,
    const float* __restrict__ g, const float* __restrict__ bta,
    float* __restrict__ C, int M, int N, int K, int act,
    int bm, int bn, unsigned short* As, unsigned short* Bs,
    float* redS, float* redSS)
{
    int tid = threadIdx.x, wave = tid >> 6, lane = tid & 63;
    int lm = lane & 15, quad = lane >> 4;
    int wm = wave >> 1, wn = wave & 1;

    f32x4 acc[2][4];
    #pragma unroll
    for (int i = 0; i < 2; ++i)
        #pragma unroll
        for (int j = 0; j < 4; ++j) acc[i][j] = (f32x4)(0.f);

    for (int k0 = 0; k0 < K; k0 += 32) {
        {
            int m = tid >> 2, kc = (tid & 3) * 8;
            const float* p = A + (size_t)(bm + m) * K + k0 + kc;
            float4 a0 = *(const float4*)p, a1 = *(const float4*)(p + 4);
            uint4 pk;
            pk.x = packbf2(a0.x, a0.y); pk.y = packbf2(a0.z, a0.w);
            pk.z = packbf2(a1.x, a1.y); pk.w = packbf2(a1.z, a1.w);
            *(uint4*)&As[m * LDAB + kc] = pk;
        }
        {
            int nn = tid & 127, kh = (tid >> 7) * 16;
            const float* p = W + (size_t)(k0 + kh) * N + bn + nn;
            float w[16];
            #pragma unroll
            for (int j = 0; j < 16; ++j) w[j] = p[(size_t)j * N];
            uint4 pk;
            pk.x = packbf2(w[0], w[1]);  pk.y = packbf2(w[2], w[3]);
            pk.z = packbf2(w[4], w[5]);  pk.w = packbf2(w[6], w[7]);
            *(uint4*)&Bs[nn * LDAB + kh] = pk;
            pk.x = packbf2(w[8], w[9]);  pk.y = packbf2(w[10], w[11]);
            pk.z = packbf2(w[12], w[13]); pk.w = packbf2(w[14], w[15]);
            *(uint4*)&Bs[nn * LDAB + kh + 8] = pk;
        }
        __syncthreads();
        bf16x8 af[2], bfr[4];
        #pragma unroll
        for (int mi = 0; mi < 2; ++mi)
            af[mi] = *(bf16x8*)&As[(wm * 32 + mi * 16 + lm) * LDAB + quad * 8];
        #pragma unroll
        for (int ni = 0; ni < 4; ++ni)
            bfr[ni] = *(bf16x8*)&Bs[(wn * 64 + ni * 16 + lm) * LDAB + quad * 8];
        #pragma unroll
        for (int mi = 0; mi < 2; ++mi)
            #pragma unroll
            for (int ni = 0; ni < 4; ++ni)
                acc[mi][ni] = __builtin_amdgcn_mfma_f32_16x16x32_bf16(
                    af[mi], bfr[ni], acc[mi][ni], 0, 0, 0);
        __syncthreads();
    }

    #pragma unroll
    for (int mi = 0; mi < 2; ++mi) {
        #pragma unroll
        for (int r = 0; r < 4; ++r) {
            int row = bm + wm * 32 + mi * 16 + quad * 4 + r;
            #pragma unroll
            for (int ni = 0; ni < 4; ++ni) {
                int col = bn + wn * 64 + ni * 16 + lm;
                float v = acc[mi][ni][r] + bias[col];
                if (R) v += R[(size_t)row * N + col];
                if (act) v = fmaxf(v, 0.f);
                acc[mi][ni][r] = v;
            }
        }
    }

    if (g) {
        #pragma unroll
        for (int mi = 0; mi < 2; ++mi) {
            #pragma unroll
            for (int r = 0; r < 4; ++r) {
                float s = 0.f, ss = 0.f;
                #pragma unroll
                for (int ni = 0; ni < 4; ++ni) {
                    float v = acc[mi][ni][r];
                    s += v; ss = fmaf(v, v, ss);
                }
                #pragma unroll
                for (int off = 1; off < 16; off <<= 1) {
                    s  += __shfl_xor(s, off, 64);
                    ss += __shfl_xor(ss, off, 64);
                }
                if (lm == 0) {
                    int lr = wm * 32 + mi * 16 + quad * 4 + r;
                    redS[wn * 64 + lr] = s;
                    redSS[wn * 64 + lr] = ss;
                }
            }
        }
        __syncthreads();
        #pragma unroll
        for (int mi = 0; mi < 2; ++mi) {
            #pragma unroll
            for (int r = 0; r < 4; ++r) {
                int lr = wm * 32 + mi * 16 + quad * 4 + r;
                int row = bm + lr;
                float s = redS[lr] + redS[64 + lr];
                float ss = redSS[lr] + redSS[64 + lr];
                float mean = s * (1.f / 128.f);
                float var = ss * (1.f / 128.f) - mean * mean;
                float rstd = rsqrtf(var + 1e-5f);
                #pragma unroll
                for (int ni = 0; ni < 4; ++ni) {
                    int col = wn * 64 + ni * 16 + lm;
                    float y = (acc[mi][ni][r] - mean) * rstd * g[col] + bta[col];
                    C[(size_t)row * 128 + col] = y;
                }
            }
        }
    } else {
        #pragma unroll
        for (int mi = 0; mi < 2; ++mi) {
            #pragma unroll
            for (int r = 0; r < 4; ++r) {
                int row = bm + wm * 32 + mi * 16 + quad * 4 + r;
                #pragma unroll
                for (int ni = 0; ni < 4; ++ni) {
                    int col = bn + wn * 64 + ni * 16 + lm;
                    C[(size_t)row * N + col] = acc[mi][ni][r];
                }
            }
        }
    }
}

// ---------------------------------------------------------------------------
// Bi-interaction core (device fn):
//   out = leaky((ego+side)@W1+b1) + leaky((ego*side)@W2+b2), K=N=128.
// BM=128 x BN=64, 4 waves stacked in m. Needs 30720 B LDS (passed in).
// ---------------------------------------------------------------------------
__device__ __forceinline__ void bi_core(
    const float* __restrict__ ego, const float* __restrict__ side,
    const float* __restrict__ W1, const float* __restrict__ b1,
    const float* __restrict__ W2, const float* __restrict__ b2,
    float* __restrict__ out, int M, int bm, int bn,
    unsigned short* Us, unsigned short* Ms,
    unsigned short* W1s, unsigned short* W2s)
{
    int tid = threadIdx.x, wave = tid >> 6, lane = tid & 63;
    int lm = lane & 15, quad = lane >> 4;

    f32x4 acc1[2][4], acc2[2][4];
    #pragma unroll
    for (int i = 0; i < 2; ++i)
        #pragma unroll
        for (int j = 0; j < 4; ++j) { acc1[i][j] = (f32x4)(0.f); acc2[i][j] = (f32x4)(0.f); }

    for (int k0 = 0; k0 < 128; k0 += 32) {
        #pragma unroll
        for (int it = 0; it < 2; ++it) {
            int i = tid + it * 256;
            int m = i >> 2, kc = (i & 3) * 8;
            int gm = bm + m;
            float e[8], s[8];
            if (gm < M) {
                const float* pe = ego + (size_t)gm * 128 + k0 + kc;
                const float* ps = side + (size_t)gm * 128 + k0 + kc;
                float4 e0 = *(const float4*)pe, e1 = *(const float4*)(pe + 4);
                float4 s0 = *(const float4*)ps, s1 = *(const float4*)(ps + 4);
                e[0]=e0.x; e[1]=e0.y; e[2]=e0.z; e[3]=e0.w;
                e[4]=e1.x; e[5]=e1.y; e[6]=e1.z; e[7]=e1.w;
                s[0]=s0.x; s[1]=s0.y; s[2]=s0.z; s[3]=s0.w;
                s[4]=s1.x; s[5]=s1.y; s[6]=s1.z; s[7]=s1.w;
            } else {
                #pragma unroll
                for (int j = 0; j < 8; ++j) { e[j] = 0.f; s[j] = 0.f; }
            }
            uint4 pu, pm;
            pu.x = packbf2(e[0]+s[0], e[1]+s[1]); pu.y = packbf2(e[2]+s[2], e[3]+s[3]);
            pu.z = packbf2(e[4]+s[4], e[5]+s[5]); pu.w = packbf2(e[6]+s[6], e[7]+s[7]);
            pm.x = packbf2(e[0]*s[0], e[1]*s[1]); pm.y = packbf2(e[2]*s[2], e[3]*s[3]);
            pm.z = packbf2(e[4]*s[4], e[5]*s[5]); pm.w = packbf2(e[6]*s[6], e[7]*s[7]);
            *(uint4*)&Us[m * LDAB + kc] = pu;
            *(uint4*)&Ms[m * LDAB + kc] = pm;
        }
        {
            int nn = tid & 63, kq = (tid >> 6) * 8;
            const float* p1 = W1 + (size_t)(k0 + kq) * 128 + bn + nn;
            const float* p2 = W2 + (size_t)(k0 + kq) * 128 + bn + nn;
            float wa[8], wb[8];
            #pragma unroll
            for (int j = 0; j < 8; ++j) { wa[j] = p1[(size_t)j * 128]; wb[j] = p2[(size_t)j * 128]; }
            uint4 pk1, pk2;
            pk1.x = packbf2(wa[0],wa[1]); pk1.y = packbf2(wa[2],wa[3]);
            pk1.z = packbf2(wa[4],wa[5]); pk1.w = packbf2(wa[6],wa[7]);
            pk2.x = packbf2(wb[0],wb[1]); pk2.y = packbf2(wb[2],wb[3]);
            pk2.z = packbf2(wb[4],wb[5]); pk2.w = packbf2(wb[6],wb[7]);
            *(uint4*)&W1s[nn * LDAB + kq] = pk1;
            *(uint4*)&W2s[nn * LDAB + kq] = pk2;
        }
        __syncthreads();
        bf16x8 au[2], am[2], bf1[4], bf2[4];
        #pragma unroll
        for (int mi = 0; mi < 2; ++mi) {
            au[mi] = *(bf16x8*)&Us[(wave * 32 + mi * 16 + lm) * LDAB + quad * 8];
            am[mi] = *(bf16x8*)&Ms[(wave * 32 + mi * 16 + lm) * LDAB + quad * 8];
        }
        #pragma unroll
        for (int ni = 0; ni < 4; ++ni) {
            bf1[ni] = *(bf16x8*)&W1s[(ni * 16 + lm) * LDAB + quad * 8];
            bf2[ni] = *(bf16x8*)&W2s[(ni * 16 + lm) * LDAB + quad * 8];
        }
        #pragma unroll
        for (int mi = 0; mi < 2; ++mi)
            #pragma unroll
            for (int ni = 0; ni < 4; ++ni) {
                acc1[mi][ni] = __builtin_amdgcn_mfma_f32_16x16x32_bf16(
                    au[mi], bf1[ni], acc1[mi][ni], 0, 0, 0);
                acc2[mi][ni] = __builtin_amdgcn_mfma_f32_16x16x32_bf16(
                    am[mi], bf2[ni], acc2[mi][ni], 0, 0, 0);
            }
        __syncthreads();
    }
    #pragma unroll
    for (int mi = 0; mi < 2; ++mi) {
        #pragma unroll
        for (int r = 0; r < 4; ++r) {
            int row = bm + wave * 32 + mi * 16 + quad * 4 + r;
            if (row < M) {
                #pragma unroll
                for (int ni = 0; ni < 4; ++ni) {
                    int col = bn + ni * 16 + lm;
                    float v1 = acc1[mi][ni][r] + b1[col];
                    v1 = v1 > 0.f ? v1 : 0.01f * v1;
                    float v2 = acc2[mi][ni][r] + b2[col];
                    v2 = v2 > 0.f ? v2 : 0.01f * v2;
                    out[(size_t)row * 128 + col] = v1 + v2;
                }
            }
        }
    }
}

// ---------------------------------------------------------------------------
// Fused kernels: blocks [0, encN) do encoder work; blocks [encN, ...) run
// spmm chunks (or bi-interaction tiles). Role branch is block-uniform.
// ---------------------------------------------------------------------------

// Q/K/V projection (+ spmm chunk): enc flatten = sel * encGy + by
__global__ __launch_bounds__(256) void qkv2_spmm(
    const float* __restrict__ A,
    const float* __restrict__ wq, const float* __restrict__ wk, const float* __restrict__ wv,
    const float* __restrict__ bq, const float* __restrict__ bk, const float* __restrict__ bv,
    float* __restrict__ Q, float* __restrict__ Ko, float* __restrict__ V, int M, int encGy,
    const unsigned int* __restrict__ egob, const float* __restrict__ vals,
    const int* __restrict__ rows, const int* __restrict__ cols,
    float* __restrict__ side, int nnz, int spmmBase, int encN)
{
    __shared__ unsigned short As[64 * LDAB];
    __shared__ unsigned short Bs[128 * LDAB];
    __shared__ float redS[128], redSS[128];
    int gid = blockIdx.x;
    if (gid >= encN) {
        spmm_block(egob, vals, rows, cols, side, nnz, spmmBase + gid - encN);
        return;
    }
    int sel = gid / encGy, by = gid % encGy;
    const float* W = (sel == 0) ? wq : (sel == 1) ? wk : wv;
    const float* b = (sel == 0) ? bq : (sel == 1) ? bk : bv;
    float* C = (sel == 0) ? Q : (sel == 1) ? Ko : V;
    gemm2_core(A, W, b, nullptr, nullptr, nullptr, C, M, 128, 128, 0,
               by * 64, 0, As, Bs, redS, redSS);
}

// generic GEMM (+LN) (+ spmm chunk): enc flatten = bx * encGy + by
__global__ __launch_bounds__(256) void gemm2_spmm(
    const float* __restrict__ A, const float* __restrict__ W,
    const float* __restrict__ bias, const float* __restrict__ R,
    const float* __restrict__ g, const float* __restrict__ bta,
    float* __restrict__ C, int M, int N, int K, int act, int encGy,
    const unsigned int* __restrict__ egob, const float* __restrict__ vals,
    const int* __restrict__ rows, const int* __restrict__ cols,
    float* __restrict__ side, int nnz, int spmmBase, int encN)
{
    __shared__ unsigned short As[64 * LDAB];
    __shared__ unsigned short Bs[128 * LDAB];
    __shared__ float redS[128], redSS[128];
    int gid = blockIdx.x;
    if (gid >= encN) {
        spmm_block(egob, vals, rows, cols, side, nnz, spmmBase + gid - encN);
        return;
    }
    int bx = gid / encGy, by = gid % encGy;
    gemm2_core(A, W, bias, R, g, bta, C, M, N, K, act,
               by * 64, bx * 128, As, Bs, redS, redSS);
}

// generic GEMM (+LN) (+ bi-interaction tiles): bi flatten bb: by=bb>>1, bx=bb&1
__global__ __launch_bounds__(256) void gemm2_bi(
    const float* __restrict__ A, const float* __restrict__ W,
    const float* __restrict__ bias, const float* __restrict__ R,
    const float* __restrict__ g, const float* __restrict__ bta,
    float* __restrict__ C, int M, int N, int K, int act, int encGy, int encN,
    const float* __restrict__ ego, const float* __restrict__ side,
    const float* __restrict__ W1, const float* __restrict__ b1,
    const float* __restrict__ W2, const float* __restrict__ b2,
    float* __restrict__ out, int Mbi, int biBase)
{
    __shared__ char smem[30720];   // max(gemm2 16384, bi 30720)
    int gid = blockIdx.x;
    if (gid < encN) {
        unsigned short* As = (unsigned short*)smem;
        unsigned short* Bs = (unsigned short*)(smem + 5120);
        float* redS  = (float*)(smem + 15360);
        float* redSS = (float*)(smem + 15360 + 512);
        int bx = gid / encGy, by = gid % encGy;
        gemm2_core(A, W, bias, R, g, bta, C, M, N, K, act,
                   by * 64, bx * 128, As, Bs, redS, redSS);
    } else {
        int bb = biBase + (gid - encN);
        unsigned short* Us  = (unsigned short*)smem;
        unsigned short* Ms  = Us + 128 * LDAB;
        unsigned short* W1s = Ms + 128 * LDAB;
        unsigned short* W2s = W1s + 64 * LDAB;
        bi_core(ego, side, W1, b1, W2, b2, out, Mbi,
                (bb >> 1) * 128, (bb & 1) * 64, Us, Ms, W1s, W2s);
    }
}

// Attention (+ spmm chunk): 256 threads = 256 queries of one (b,h); K/V
// staged once per 128-row chunk and shared by all queries (half the staging
// of the old 2-blocks-per-bh layout). Online softmax identical numerics.
__global__ __launch_bounds__(256) void attn_spmm(
    const float* __restrict__ q, const float* __restrict__ k,
    const float* __restrict__ v, float* __restrict__ o, int NH,
    const unsigned int* __restrict__ egob, const float* __restrict__ vals,
    const int* __restrict__ rows, const int* __restrict__ cols,
    float* __restrict__ side, int nnz, int spmmBase, int encN)
{
    const int L = 256, DK = 16;
    __shared__ float Ks[128 * DK];
    __shared__ float Vs[128 * DK];
    int gid = blockIdx.x;
    if (gid >= encN) {
        spmm_block(egob, vals, rows, cols, side, nnz, spmmBase + gid - encN);
        return;
    }
    int b = gid / NH, h = gid % NH;
    int tid = threadIdx.x;

    size_t qbase = ((size_t)(b * L + tid) * NH + h) * DK;
    float qr[16];
    #pragma unroll
    for (int d4 = 0; d4 < 4; ++d4) {
        float4 t = *(const float4*)(q + qbase + d4 * 4);
        qr[d4*4+0] = t.x * 0.25f; qr[d4*4+1] = t.y * 0.25f;
        qr[d4*4+2] = t.z * 0.25f; qr[d4*4+3] = t.w * 0.25f;
    }
    float acc[16];
    #pragma unroll
    for (int d = 0; d < 16; ++d) acc[d] = 0.f;
    float mmax = -1e30f, ssum = 0.f;

    for (int c0 = 0; c0 < L; c0 += 128) {
        __syncthreads();
        for (int i = tid; i < 128 * 4; i += 256) {
            int ll = i >> 2, d4 = (i & 3) * 4;
            size_t gg = ((size_t)(b * L + c0 + ll) * NH + h) * DK + d4;
            *(float4*)&Ks[ll * 16 + d4] = *(const float4*)(k + gg);
            *(float4*)&Vs[ll * 16 + d4] = *(const float4*)(v + gg);
        }
        __syncthreads();

        for (int kk = 0; kk < 128; ++kk) {
            float dot = 0.f;
            #pragma unroll
            for (int d4 = 0; d4 < 4; ++d4) {
                float4 kv = *(const float4*)&Ks[kk * 16 + d4 * 4];
                dot = fmaf(qr[d4*4+0], kv.x, dot);
                dot = fmaf(qr[d4*4+1], kv.y, dot);
                dot = fmaf(qr[d4*4+2], kv.z, dot);
                dot = fmaf(qr[d4*4+3], kv.w, dot);
            }
            if (dot > mmax) {
                float alpha = __expf(mmax - dot);
                ssum *= alpha;
                #pragma unroll
                for (int d = 0; d < 16; ++d) acc[d] *= alpha;
                mmax = dot;
            }
            float p = __expf(dot - mmax);
            ssum += p;
            #pragma unroll
            for (int d4 = 0; d4 < 4; ++d4) {
                float4 vv = *(const float4*)&Vs[kk * 16 + d4 * 4];
                acc[d4*4+0] = fmaf(p, vv.x, acc[d4*4+0]);
                acc[d4*4+1] = fmaf(p, vv.y, acc[d4*4+1]);
                acc[d4*4+2] = fmaf(p, vv.z, acc[d4*4+2]);
                acc[d4*4+3] = fmaf(p, vv.w, acc[d4*4+3]);
            }
        }
    }
    float inv = 1.f / ssum;
    #pragma unroll
    for (int d4 = 0; d4 < 4; ++d4) {
        float4 t;
        t.x = acc[d4*4+0] * inv; t.y = acc[d4*4+1] * inv;
        t.z = acc[d4*4+2] * inv; t.w = acc[d4*4+3] * inv;
        *(float4*)(o + qbase + d4 * 4) = t;
    }
}

extern "C" void kernel_launch(void* const* d_in, const int* in_sizes, int n_in,
                              void* d_out, int out_size, void* d_ws, size_t ws_size,
                              hipStream_t stream) {
    const float* ego    = (const float*)d_in[0];
    const float* vals   = (const float*)d_in[1];
    const float* W1     = (const float*)d_in[2];
    const float* b1     = (const float*)d_in[3];
    const float* W2     = (const float*)d_in[4];
    const float* b2     = (const float*)d_in[5];
    const float* enc_in = (const float*)d_in[6];
    const float* wq  = (const float*)d_in[7];
    const float* bq  = (const float*)d_in[8];
    const float* wk  = (const float*)d_in[9];
    const float* bk  = (const float*)d_in[10];
    const float* wv  = (const float*)d_in[11];
    const float* bv  = (const float*)d_in[12];
    const float* wo  = (const float*)d_in[13];
    const float* bo  = (const float*)d_in[14];
    const float* ln1_g = (const float*)d_in[15];
    const float* ln1_b = (const float*)d_in[16];
    const float* cw1 = (const float*)d_in[17];
    const float* cb1 = (const float*)d_in[18];
    const float* cw2 = (const float*)d_in[19];
    const float* cb2 = (const float*)d_in[20];
    const float* ln2_g = (const float*)d_in[21];
    const float* ln2_b = (const float*)d_in[22];
    const int* rows = (const int*)d_in[23];
    const int* cols = (const int*)d_in[24];

    const int D = 128, DI = 512, NH = 8, L = 256;
    const int Nn   = in_sizes[0] / D;        // 100000
    const int nnz  = in_sizes[1];            // 2000000
    const int NL   = in_sizes[7] / (D * D);  // 2
    const int Menc = in_sizes[6] / D;        // 8192 (= B*L)
    const int Bb   = Menc / L;               // 32

    float* ws = (float*)d_ws;
    size_t off = 0;
    float* side = ws + off; off += (size_t)Nn * D;
    float* Qb = ws + off; off += (size_t)Menc * D;
    float* Kb = ws + off; off += (size_t)Menc * D;
    float* Vb = ws + off; off += (size_t)Menc * D;
    float* Ob = ws + off; off += (size_t)Menc * D;
    float* XA = ws + off; off += (size_t)Menc * D;
    float* XB = ws + off; off += (size_t)Menc * D;
    float* Hb = ws + off; off += (size_t)Menc * DI;
    unsigned int* egob = (unsigned int*)(ws + off); off += (size_t)Nn * (D / 2); // bf16 ego

    float* outAgg = (float*)d_out;
    float* outX   = (float*)d_out + (size_t)Nn * D;

    // ---- prologue: side=0, ego->bf16 (both must precede spmm chunks) ----
    hipMemsetAsync(side, 0, (size_t)Nn * D * sizeof(float), stream);
    ego2bf16_kernel<<<2048, 256, 0, stream>>>(ego, egob, (size_t)Nn * (D / 4));

    // ---- fused schedule: spmm chunks ride the first 5*NL-2 encoder stages;
    //      bi-interaction halves ride the last two (after all chunks). ----
    const int spmmBlocks = (nnz + 255) / 256;
    const int nStages = 5 * NL - 2;
    const int per = (spmmBlocks + nStages - 1) / nStages;
    const int encGy = Menc / 64;
    const int biGy = (Nn + 127) / 128;
    int ci = 0;

    const float* x = enc_in;
    for (int i = 0; i < NL; ++i) {
        const size_t wOff = (size_t)i * D * D;
        int base, cnt;
        #define NEXT_CHUNK  base = ci * per; cnt = spmmBlocks - base; \
                            if (cnt < 0) cnt = 0; if (cnt > per) cnt = per; ci++

        // Q/K/V projection
        NEXT_CHUNK;
        qkv2_spmm<<<3 * encGy + cnt, 256, 0, stream>>>(
            x, wq + wOff, wk + wOff, wv + wOff,
            bq + (size_t)i * D, bk + (size_t)i * D, bv + (size_t)i * D,
            Qb, Kb, Vb, Menc, encGy,
            egob, vals, rows, cols, side, nnz, base, 3 * encGy);

        // attention
        NEXT_CHUNK;
        attn_spmm<<<Bb * NH + cnt, 256, 0, stream>>>(
            Qb, Kb, Vb, Ob, NH,
            egob, vals, rows, cols, side, nnz, base, Bb * NH);

        // MHA out-proj + residual + LN1
        NEXT_CHUNK;
        gemm2_spmm<<<encGy + cnt, 256, 0, stream>>>(
            Ob, wo + wOff, bo + (size_t)i * D, x,
            ln1_g + (size_t)i * D, ln1_b + (size_t)i * D, XA, Menc, D, D, 0, encGy,
            egob, vals, rows, cols, side, nnz, base, encGy);

        // FFN up + relu
        if (i < NL - 1) {
            NEXT_CHUNK;
            gemm2_spmm<<<4 * encGy + cnt, 256, 0, stream>>>(
                XA, cw1 + (size_t)i * D * DI, cb1 + (size_t)i * DI, nullptr,
                nullptr, nullptr, Hb, Menc, DI, D, 1, encGy,
                egob, vals, rows, cols, side, nnz, base, 4 * encGy);
        } else {
            gemm2_bi<<<4 * encGy + biGy, 256, 0, stream>>>(
                XA, cw1 + (size_t)i * D * DI, cb1 + (size_t)i * DI, nullptr,
                nullptr, nullptr, Hb, Menc, DI, D, 1, encGy, 4 * encGy,
                ego, side, W1, b1, W2, b2, outAgg, Nn, 0);
        }

        // FFN down + residual + LN2
        float* dst = (i == NL - 1) ? outX : XB;
        if (i < NL - 1) {
            NEXT_CHUNK;
            gemm2_spmm<<<encGy + cnt, 256, 0, stream>>>(
                Hb, cw2 + (size_t)i * DI * D, cb2 + (size_t)i * D, XA,
                ln2_g + (size_t)i * D, ln2_b + (size_t)i * D, dst, Menc, D, DI, 0, encGy,
                egob, vals, rows, cols, side, nnz, base, encGy);
        } else {
            gemm2_bi<<<encGy + biGy, 256, 0, stream>>>(
                Hb, cw2 + (size_t)i * DI * D, cb2 + (size_t)i * D, XA,
                ln2_g + (size_t)i * D, ln2_b + (size_t)i * D, dst, Menc, D, DI, 0, encGy, encGy,
                ego, side, W1, b1, W2, b2, outAgg, Nn, biGy);
        }
        #undef NEXT_CHUNK
        x = XB;
    }
}